// Round 3
// baseline (1933.793 us; speedup 1.0000x reference)
//
#include <hip/hip_runtime.h>
#include <hip/hip_bf16.h>
#include <math.h>

#define D 64
#define EPSF 1e-6f
#define EPS2F 1e-12f
#define PROJ_EPSF 1e-5f

typedef __hip_bfloat16 bf16;

__device__ __forceinline__ float bf2f(bf16 b) { return __bfloat162float(b); }

template <typename T> __device__ __forceinline__ float ldT(const T* p, size_t i);
template <> __device__ __forceinline__ float ldT<float>(const float* p, size_t i) { return p[i]; }
template <> __device__ __forceinline__ float ldT<bf16>(const bf16* p, size_t i) { return bf2f(p[i]); }

template <typename T> __device__ __forceinline__ void stT(T* p, size_t i, float v);
template <> __device__ __forceinline__ void stT<float>(float* p, size_t i, float v) { p[i] = v; }
template <> __device__ __forceinline__ void stT<bf16>(bf16* p, size_t i, float v) { p[i] = __float2bfloat16(v); }

// ---- wave-wide sum (64 lanes) ----------------------------------------------
__device__ __forceinline__ float wave_sum(float v) {
#pragma unroll
    for (int o = 32; o > 0; o >>= 1) v += __shfl_xor(v, o, 64);
    return v;
}

// ---- per-lane hyperbolic ops; lane holds one of 64 components --------------
__device__ __forceinline__ float hyp_proj_lane(float x) {
    float n = sqrtf(fmaxf(wave_sum(x * x), EPS2F));
    float scale = fminf((1.0f - PROJ_EPSF) / n, 1.0f);
    return x * scale;
}

__device__ __forceinline__ float exp_map_lane(float v) {
    float n = sqrtf(fmaxf(wave_sum(v * v), EPS2F));
    return tanhf(n) * v / n;
}

__device__ __forceinline__ float log_map_lane(float y) {
    float n = sqrtf(fmaxf(wave_sum(y * y), EPS2F));
    return atanhf(fminf(n, 1.0f - PROJ_EPSF)) * y / n;
}

__device__ __forceinline__ float mobius_add_lane(float x, float y) {
    float x2 = wave_sum(x * x);
    float y2 = wave_sum(y * y);
    float xy = wave_sum(x * y);
    float num = (1.0f + 2.0f * xy + y2) * x + (1.0f - x2) * y;
    float den = 1.0f + 2.0f * xy + x2 * y2;
    return num / fmaxf(den, EPSF);
}

// ---- stage 1: e0 = proj(x); pre1 = log(e0); h = pre1 @ W1 ------------------
template <typename HT>
__global__ __launch_bounds__(256) void node_stage1(
    const float* __restrict__ x, const float* __restrict__ W,
    HT* __restrict__ h_out, int N)
{
    __shared__ float Wl[D * D];
    for (int i = threadIdx.x; i < D * D; i += blockDim.x) Wl[i] = W[i];
    __syncthreads();

    const int lane = threadIdx.x & 63;
    const int wpb = blockDim.x >> 6;
    int node = blockIdx.x * wpb + (threadIdx.x >> 6);
    const int stride = gridDim.x * wpb;

    for (; node < N; node += stride) {
        float e0 = hyp_proj_lane(x[(size_t)node * D + lane]);
        float pre = log_map_lane(e0);
        float acc = 0.0f;
#pragma unroll
        for (int k = 0; k < D; ++k)
            acc = fmaf(__shfl(pre, k, 64), Wl[k * D + lane], acc);
        stT(h_out, (size_t)node * D + lane, acc);
    }
}

// ---- edge SpMM over row range [r0,r1): agg[r-r0] += val * h[c] -------------
template <typename HT>
__global__ __launch_bounds__(256) void edge_spmm(
    const int* __restrict__ rows, const int* __restrict__ cols,
    const float* __restrict__ vals, const HT* __restrict__ h,
    float* __restrict__ agg, int E, int r0, int r1)
{
    const int lane = threadIdx.x & 63;
    const int wpb = blockDim.x >> 6;
    int e = blockIdx.x * wpb + (threadIdx.x >> 6);
    const int stride = gridDim.x * wpb;

    for (; e < E; e += stride) {
        int r = rows[e];
        if (r < r0 || r >= r1) continue;
        int c = cols[e];
        float v = vals[e];
        float hv = ldT(h, (size_t)c * D + lane);
        atomicAdd(&agg[(size_t)(r - r0) * D + lane], v * hv);
    }
}

// ---- stage 2 (nodes [c0,c0+cn)): layer-1 epilogue + residual + L2 linear ---
template <typename H1T, typename H2T>
__global__ __launch_bounds__(256) void node_stage2(
    const float* __restrict__ agg, const float* __restrict__ b,
    const float* __restrict__ x, const float* __restrict__ W2,
    H1T* __restrict__ h1_out, H2T* __restrict__ h2lin_out, int c0, int cn)
{
    __shared__ float Wl[D * D];
    for (int i = threadIdx.x; i < D * D; i += blockDim.x) Wl[i] = W2[i];
    __syncthreads();

    const int lane = threadIdx.x & 63;
    const int wpb = blockDim.x >> 6;
    int idx = blockIdx.x * wpb + (threadIdx.x >> 6);
    const int stride = gridDim.x * wpb;

    float bh = hyp_proj_lane(exp_map_lane(b[lane]));

    for (; idx < cn; idx += stride) {
        int node = c0 + idx;
        float a = agg[(size_t)idx * D + lane];
        float out = hyp_proj_lane(exp_map_lane(a));
        out = hyp_proj_lane(mobius_add_lane(out, bh));
        out = hyp_proj_lane(exp_map_lane(tanhf(log_map_lane(out))));   // activation
        float e0 = hyp_proj_lane(x[(size_t)node * D + lane]);          // recompute e0
        float h1 = hyp_proj_lane(mobius_add_lane(out, e0));
        stT(h1_out, (size_t)node * D + lane, h1);
        float pre = log_map_lane(h1);
        float acc = 0.0f;
#pragma unroll
        for (int k = 0; k < D; ++k)
            acc = fmaf(__shfl(pre, k, 64), Wl[k * D + lane], acc);
        stT(h2lin_out, (size_t)node * D + lane, acc);
    }
}

// ---- stage 3 (nodes [c0,c0+cn)): layer-2 epilogue + residual ---------------
template <typename H1T, typename OT>
__global__ __launch_bounds__(256) void node_stage3(
    const float* __restrict__ agg, const float* __restrict__ b,
    const H1T* __restrict__ h1, OT* __restrict__ out, int c0, int cn)
{
    const int lane = threadIdx.x & 63;
    const int wpb = blockDim.x >> 6;
    int idx = blockIdx.x * wpb + (threadIdx.x >> 6);
    const int stride = gridDim.x * wpb;

    float bh = hyp_proj_lane(exp_map_lane(b[lane]));

    for (; idx < cn; idx += stride) {
        int node = c0 + idx;
        float a = agg[(size_t)idx * D + lane];
        float o = hyp_proj_lane(exp_map_lane(a));
        o = hyp_proj_lane(mobius_add_lane(o, bh));
        float h1v = ldT(h1, (size_t)node * D + lane);
        float h2 = hyp_proj_lane(mobius_add_lane(o, h1v));
        stT(out, (size_t)node * D + lane, h2);
    }
}

// ---- bf16 -> fp32 expand (chunked path only) -------------------------------
__global__ __launch_bounds__(256) void expand_bf16(
    const bf16* __restrict__ src, float* __restrict__ dst, size_t n)
{
    size_t i = (size_t)blockIdx.x * blockDim.x + threadIdx.x;
    size_t stride = (size_t)gridDim.x * blockDim.x;
    for (; i < n; i += stride) dst[i] = bf2f(src[i]);
}

extern "C" void kernel_launch(void* const* d_in, const int* in_sizes, int n_in,
                              void* d_out, int out_size, void* d_ws, size_t ws_size,
                              hipStream_t stream) {
    const float* x    = (const float*)d_in[0];
    const float* vals = (const float*)d_in[1];
    const float* W1   = (const float*)d_in[2];
    const float* b1   = (const float*)d_in[3];
    const float* W2   = (const float*)d_in[4];
    const float* b2   = (const float*)d_in[5];
    const int* rows   = (const int*)d_in[6];
    const int* cols   = (const int*)d_in[7];
    float* out = (float*)d_out;

    const int N = in_sizes[0] / D;
    const int E = in_sizes[1];
    const size_t nd = (size_t)N * D;

    const int TB = 256;
    const int node_blocks = 1024;
    const int edge_blocks = 16384;

    const size_t needA = nd * 4 * 2;            // agg fp32 + h1 fp32 (51.2 MB)
    const size_t needB = nd * 4 + nd * 2;       // agg fp32 + h1 bf16 (38.4 MB)

    if (ws_size >= needA) {
        float* agg = (float*)d_ws;
        float* h1  = agg + nd;
        float* h   = out;                        // d_out doubles as h / h2lin scratch
        node_stage1<float><<<node_blocks, TB, 0, stream>>>(x, W1, h, N);
        hipMemsetAsync(agg, 0, nd * 4, stream);
        edge_spmm<float><<<edge_blocks, TB, 0, stream>>>(rows, cols, vals, h, agg, E, 0, N);
        node_stage2<float, float><<<node_blocks, TB, 0, stream>>>(agg, b1, x, W2, h1, h, 0, N);
        hipMemsetAsync(agg, 0, nd * 4, stream);
        edge_spmm<float><<<edge_blocks, TB, 0, stream>>>(rows, cols, vals, h, agg, E, 0, N);
        node_stage3<float, float><<<node_blocks, TB, 0, stream>>>(agg, b2, h1, out, 0, N);
    } else if (ws_size >= needB) {
        float* agg = (float*)d_ws;
        bf16*  h1  = (bf16*)(agg + nd);
        float* h   = out;
        node_stage1<float><<<node_blocks, TB, 0, stream>>>(x, W1, h, N);
        hipMemsetAsync(agg, 0, nd * 4, stream);
        edge_spmm<float><<<edge_blocks, TB, 0, stream>>>(rows, cols, vals, h, agg, E, 0, N);
        node_stage2<bf16, float><<<node_blocks, TB, 0, stream>>>(agg, b1, x, W2, h1, h, 0, N);
        hipMemsetAsync(agg, 0, nd * 4, stream);
        edge_spmm<float><<<edge_blocks, TB, 0, stream>>>(rows, cols, vals, h, agg, E, 0, N);
        node_stage3<bf16, float><<<node_blocks, TB, 0, stream>>>(agg, b2, h1, out, 0, N);
    } else {
        // Chunked path: h (bf16) in d_out[0:nd], h2lin (bf16) in d_out[nd:2nd],
        // h1 (bf16) in ws, agg (fp32, chunk of nodes) after it. Final result
        // written bf16 over h1, then expanded to fp32 into d_out.
        bf16* h     = (bf16*)d_out;
        bf16* h2    = (bf16*)d_out + nd;
        bf16* h1    = (bf16*)d_ws;
        float* agg  = (float*)((char*)d_ws + nd * 2);
        size_t avail = (ws_size > nd * 2) ? (ws_size - nd * 2) : 0;
        int chunkN = (int)(avail / (D * 4));
        if (chunkN < 1) chunkN = 1;              // degenerate; correctness over speed
        if (chunkN > N) chunkN = N;

        node_stage1<bf16><<<node_blocks, TB, 0, stream>>>(x, W1, h, N);
        for (int c0 = 0; c0 < N; c0 += chunkN) {
            int cn = (c0 + chunkN <= N) ? chunkN : (N - c0);
            hipMemsetAsync(agg, 0, (size_t)cn * D * 4, stream);
            edge_spmm<bf16><<<edge_blocks, TB, 0, stream>>>(rows, cols, vals, h, agg, E, c0, c0 + cn);
            node_stage2<bf16, bf16><<<node_blocks, TB, 0, stream>>>(agg, b1, x, W2, h1, h2, c0, cn);
        }
        for (int c0 = 0; c0 < N; c0 += chunkN) {
            int cn = (c0 + chunkN <= N) ? chunkN : (N - c0);
            hipMemsetAsync(agg, 0, (size_t)cn * D * 4, stream);
            edge_spmm<bf16><<<edge_blocks, TB, 0, stream>>>(rows, cols, vals, h2, agg, E, c0, c0 + cn);
            node_stage3<bf16, bf16><<<node_blocks, TB, 0, stream>>>(agg, b2, h1, h1, c0, cn);
        }
        expand_bf16<<<2048, TB, 0, stream>>>(h1, out, nd);
    }
}

// Round 4
// 1222.504 us; speedup vs baseline: 1.5818x; 1.5818x over previous
//
#include <hip/hip_runtime.h>
#include <hip/hip_fp16.h>
#include <math.h>

#define D 64
#define EPSF 1e-6f
#define EPS2F 1e-12f
#define PROJ_EPSF 1e-5f

// ---- wave-wide sum (64 lanes) ----------------------------------------------
__device__ __forceinline__ float wave_sum(float v) {
#pragma unroll
    for (int o = 32; o > 0; o >>= 1) v += __shfl_xor(v, o, 64);
    return v;
}

// ---- per-lane hyperbolic ops; lane holds one of 64 components --------------
__device__ __forceinline__ float hyp_proj_lane(float x) {
    float n = sqrtf(fmaxf(wave_sum(x * x), EPS2F));
    float scale = fminf((1.0f - PROJ_EPSF) / n, 1.0f);
    return x * scale;
}

__device__ __forceinline__ float exp_map_lane(float v) {
    float n = sqrtf(fmaxf(wave_sum(v * v), EPS2F));
    return tanhf(n) * v / n;
}

__device__ __forceinline__ float log_map_lane(float y) {
    float n = sqrtf(fmaxf(wave_sum(y * y), EPS2F));
    return atanhf(fminf(n, 1.0f - PROJ_EPSF)) * y / n;
}

__device__ __forceinline__ float mobius_add_lane(float x, float y) {
    float x2 = wave_sum(x * x);
    float y2 = wave_sum(y * y);
    float xy = wave_sum(x * y);
    float num = (1.0f + 2.0f * xy + y2) * x + (1.0f - x2) * y;
    float den = 1.0f + 2.0f * xy + x2 * y2;
    return num / fmaxf(den, EPSF);
}

// ---- CSR build: count ------------------------------------------------------
__global__ __launch_bounds__(256) void count_rows(
    const int* __restrict__ rows, int* __restrict__ rs, int E)
{
    int e = blockIdx.x * 256 + threadIdx.x;
    if (e < E) atomicAdd(&rs[rows[e]], 1);
}

// ---- CSR build: single-block exclusive scan over rs[0..N) ------------------
__global__ __launch_bounds__(1024) void scan_excl(int* __restrict__ rs, int N)
{
    __shared__ int wsum[16];
    __shared__ int carry;
    __shared__ int ctot;
    const int lane = threadIdx.x & 63;
    const int wid  = threadIdx.x >> 6;
    if (threadIdx.x == 0) carry = 0;
    __syncthreads();
    for (int c0 = 0; c0 < N; c0 += 1024) {
        int i = c0 + threadIdx.x;
        int v = (i < N) ? rs[i] : 0;
        int acc = v;
#pragma unroll
        for (int off = 1; off < 64; off <<= 1) {
            int t = __shfl_up(acc, off, 64);
            if (lane >= off) acc += t;
        }
        if (lane == 63) wsum[wid] = acc;
        __syncthreads();
        if (wid == 0) {
            int w = (lane < 16) ? wsum[lane] : 0;
            int a = w;
#pragma unroll
            for (int off = 1; off < 16; off <<= 1) {
                int t = __shfl_up(a, off, 64);
                if (lane >= off) a += t;
            }
            if (lane < 16) wsum[lane] = a - w;   // exclusive base per wave
            if (lane == 15) ctot = a;            // chunk total
        }
        __syncthreads();
        if (i < N) rs[i] = carry + wsum[wid] + (acc - v);
        __syncthreads();
        if (threadIdx.x == 0) carry += ctot;
        __syncthreads();
    }
}

// ---- CSR build: scatter (destroys rs into inclusive form) ------------------
// After this, row r's edges live at [r==0?0:rs[r-1], rs[r]).
__global__ __launch_bounds__(256) void scatter_edges(
    const int* __restrict__ rows, const int* __restrict__ cols,
    const float* __restrict__ vals, int* __restrict__ rs,
    int* __restrict__ ecol, __half* __restrict__ eval, int E)
{
    int e = blockIdx.x * 256 + threadIdx.x;
    if (e < E) {
        int pos = atomicAdd(&rs[rows[e]], 1);
        ecol[pos] = cols[e];
        eval[pos] = __float2half(vals[e]);
    }
}

// ---- k1: h = (log(proj(x))) @ W1, stored fp16 ------------------------------
__global__ __launch_bounds__(256) void node_stage1(
    const float* __restrict__ x, const float* __restrict__ W,
    __half* __restrict__ h, int N)
{
    __shared__ float Wl[D * D];
    for (int i = threadIdx.x; i < D * D; i += 256) Wl[i] = W[i];
    __syncthreads();
    const int lane = threadIdx.x & 63;
    int node = blockIdx.x * 4 + (threadIdx.x >> 6);
    if (node >= N) return;
    float e0 = hyp_proj_lane(x[(size_t)node * D + lane]);
    float pre = log_map_lane(e0);
    float acc = 0.0f;
#pragma unroll
    for (int k = 0; k < D; ++k)
        acc = fmaf(__shfl(pre, k, 64), Wl[k * D + lane], acc);
    h[(size_t)node * D + lane] = __float2half(acc);
}

// ---- CSR gather-accumulate helper: acc_lane = sum_j val_j * h[col_j][lane] -
__device__ __forceinline__ float csr_accumulate(
    const int* __restrict__ rs, const int* __restrict__ ecol,
    const __half* __restrict__ eval, const __half* __restrict__ h,
    int row, int lane)
{
    int start = (row == 0) ? 0 : rs[row - 1];
    int end = rs[row];
    float acc = 0.0f;
    for (int j0 = start; j0 < end; j0 += 64) {
        int cnt = end - j0; if (cnt > 64) cnt = 64;
        int c = 0; float v = 0.0f;
        if (lane < cnt) {                       // coalesced batch load
            c = ecol[j0 + lane];
            v = __half2float(eval[j0 + lane]);
        }
        for (int t = 0; t < cnt; ++t) {         // broadcast via shuffle
            int   ct = __shfl(c, t, 64);
            float vt = __shfl(v, t, 64);
            acc = fmaf(vt, __half2float(h[(size_t)ct * D + lane]), acc);
        }
    }
    return acc;
}

// ---- k2: fused layer-1 SpMM + epilogue + residual + layer-2 linear ---------
__global__ __launch_bounds__(256) void layer1_fused(
    const int* __restrict__ rs, const int* __restrict__ ecol,
    const __half* __restrict__ eval, const __half* __restrict__ h,
    const float* __restrict__ x, const float* __restrict__ b,
    const float* __restrict__ W2, __half* __restrict__ h1_out,
    __half* __restrict__ h2lin_out, int N)
{
    __shared__ float Wl[D * D];
    for (int i = threadIdx.x; i < D * D; i += 256) Wl[i] = W2[i];
    __syncthreads();
    const int lane = threadIdx.x & 63;
    int row = blockIdx.x * 4 + (threadIdx.x >> 6);
    if (row >= N) return;

    float bh = hyp_proj_lane(exp_map_lane(b[lane]));
    float acc = csr_accumulate(rs, ecol, eval, h, row, lane);

    float out = hyp_proj_lane(exp_map_lane(acc));
    out = hyp_proj_lane(mobius_add_lane(out, bh));
    out = hyp_proj_lane(exp_map_lane(tanhf(log_map_lane(out))));   // activation
    float e0 = hyp_proj_lane(x[(size_t)row * D + lane]);           // recompute e0
    float h1 = hyp_proj_lane(mobius_add_lane(out, e0));
    h1_out[(size_t)row * D + lane] = __float2half(h1);

    float pre = log_map_lane(h1);                                  // layer-2 linear
    float a2 = 0.0f;
#pragma unroll
    for (int k = 0; k < D; ++k)
        a2 = fmaf(__shfl(pre, k, 64), Wl[k * D + lane], a2);
    h2lin_out[(size_t)row * D + lane] = __float2half(a2);
}

// ---- k3: fused layer-2 SpMM + epilogue + residual; writes over h1 slot -----
__global__ __launch_bounds__(256) void layer2_fused(
    const int* __restrict__ rs, const int* __restrict__ ecol,
    const __half* __restrict__ eval, const __half* __restrict__ h2lin,
    const float* __restrict__ b, __half* __restrict__ h1_inout, int N)
{
    const int lane = threadIdx.x & 63;
    int row = blockIdx.x * 4 + (threadIdx.x >> 6);
    if (row >= N) return;

    float bh = hyp_proj_lane(exp_map_lane(b[lane]));
    float acc = csr_accumulate(rs, ecol, eval, h2lin, row, lane);

    float o = hyp_proj_lane(exp_map_lane(acc));
    o = hyp_proj_lane(mobius_add_lane(o, bh));
    float h1v = __half2float(h1_inout[(size_t)row * D + lane]);
    float h2 = hyp_proj_lane(mobius_add_lane(o, h1v));
    h1_inout[(size_t)row * D + lane] = __float2half(h2);   // same slot, own row only
}

// ---- k4: fp16 temp -> fp32 output ------------------------------------------
__global__ __launch_bounds__(256) void expand_half(
    const __half* __restrict__ src, float* __restrict__ dst, int n)
{
    int i = blockIdx.x * 256 + threadIdx.x;
    if (i < n) dst[i] = __half2float(src[i]);
}

extern "C" void kernel_launch(void* const* d_in, const int* in_sizes, int n_in,
                              void* d_out, int out_size, void* d_ws, size_t ws_size,
                              hipStream_t stream) {
    const float* x    = (const float*)d_in[0];
    const float* vals = (const float*)d_in[1];
    const float* W1   = (const float*)d_in[2];
    const float* b1   = (const float*)d_in[3];
    const float* W2   = (const float*)d_in[4];
    const float* b2   = (const float*)d_in[5];
    const int* rows   = (const int*)d_in[6];
    const int* cols   = (const int*)d_in[7];
    float* out = (float*)d_out;

    const int N = in_sizes[0] / D;
    const int E = in_sizes[1];
    const size_t nd = (size_t)N * D;

    // workspace layout (fits 32.4 MB, measured ws_size >= 38.4 MB):
    //   ecol: E int32 | eval: E fp16 | h1: nd fp16 | rs: (N+1) int32
    int*    ecol = (int*)d_ws;
    __half* eval = (__half*)((char*)d_ws + (size_t)E * 4);
    __half* h1   = (__half*)((char*)d_ws + (size_t)E * 6);
    int*    rs   = (int*)((char*)d_ws + (size_t)E * 6 + nd * 2);

    // d_out doubles as fp16 scratch until the final expand:
    __half* h     = (__half*)d_out;        // bytes [0, 2nd)
    __half* h2lin = h + nd;                // bytes [2nd, 4nd)

    const int eb = (E + 255) / 256;
    const int nb = (N + 3) / 4;

    // CSR build (reused by both layers)
    hipMemsetAsync(rs, 0, (size_t)(N + 1) * 4, stream);
    count_rows<<<eb, 256, 0, stream>>>(rows, rs, E);
    scan_excl<<<1, 1024, 0, stream>>>(rs, N);
    scatter_edges<<<eb, 256, 0, stream>>>(rows, cols, vals, rs, ecol, eval, E);

    // pipeline
    node_stage1<<<nb, 256, 0, stream>>>(x, W1, h, N);
    layer1_fused<<<nb, 256, 0, stream>>>(rs, ecol, eval, h, x, b1, W2, h1, h2lin, N);
    layer2_fused<<<nb, 256, 0, stream>>>(rs, ecol, eval, h2lin, b2, h1, N);
    expand_half<<<(int)((nd + 255) / 256), 256, 0, stream>>>(h1, out, (int)nd);
}

// Round 5
// 877.810 us; speedup vs baseline: 2.2030x; 1.3927x over previous
//
#include <hip/hip_runtime.h>
#include <math.h>

#define D 64
#define EPSF 1e-6f
#define EPS2F 1e-12f
#define PROJ_EPSF 1e-5f

typedef _Float16 f16;
typedef f16 f16x2 __attribute__((ext_vector_type(2)));
typedef f16 f16x8 __attribute__((ext_vector_type(8)));
typedef float f32x4 __attribute__((ext_vector_type(4)));

// ---- wave-wide sum (64 lanes) ----------------------------------------------
__device__ __forceinline__ float wave_sum(float v) {
#pragma unroll
    for (int o = 32; o > 0; o >>= 1) v += __shfl_xor(v, o, 64);
    return v;
}

__device__ __forceinline__ float hyp_proj_lane(float x) {
    float n = sqrtf(fmaxf(wave_sum(x * x), EPS2F));
    return x * fminf((1.0f - PROJ_EPSF) / n, 1.0f);
}
__device__ __forceinline__ float exp_map_lane(float v) {
    float n = sqrtf(fmaxf(wave_sum(v * v), EPS2F));
    return tanhf(n) * v / n;
}
__device__ __forceinline__ float log_map_lane(float y) {
    float n = sqrtf(fmaxf(wave_sum(y * y), EPS2F));
    return atanhf(fminf(n, 1.0f - PROJ_EPSF)) * y / n;
}
__device__ __forceinline__ float mobius_add_lane(float x, float y) {
    float x2 = wave_sum(x * x);
    float y2 = wave_sum(y * y);
    float xy = wave_sum(x * y);
    float num = (1.0f + 2.0f * xy + y2) * x + (1.0f - x2) * y;
    float den = 1.0f + 2.0f * xy + x2 * y2;
    return num / fmaxf(den, EPSF);
}

// ========================= CSR build ========================================
__global__ __launch_bounds__(256) void count_rows(
    const int* __restrict__ rows, int* __restrict__ rs, int E)
{
    int e = blockIdx.x * 256 + threadIdx.x;
    if (e < E) atomicAdd(&rs[rows[e]], 1);
}

// per-1024 chunk totals (N % 4 == 0 assumed; guarded at int4 granularity)
__global__ __launch_bounds__(256) void chunk_reduce(
    const int* __restrict__ rs, int* __restrict__ part, int N)
{
    __shared__ int ws[4];
    int t = threadIdx.x, lane = t & 63, wid = t >> 6;
    int idx0 = blockIdx.x * 1024 + t * 4;
    int s = 0;
    if (idx0 < N) { int4 v = *(const int4*)(rs + idx0); s = v.x + v.y + v.z + v.w; }
    s = (int)wave_sum((float)s);   // exact: degrees sum < 2^24 per wave chunk
    if (lane == 0) ws[wid] = s;
    __syncthreads();
    if (t == 0) part[blockIdx.x] = ws[0] + ws[1] + ws[2] + ws[3];
}

// exclusive scan of P chunk totals, single wave
__global__ __launch_bounds__(64) void scan_parts(int* __restrict__ part, int P)
{
    int lane = threadIdx.x;
    int carry = 0;
    for (int b = 0; b < P; b += 64) {
        int i = b + lane;
        int v = (i < P) ? part[i] : 0;
        int inc = v;
#pragma unroll
        for (int off = 1; off < 64; off <<= 1) {
            int tu = __shfl_up(inc, off, 64);
            if (lane >= off) inc += tu;
        }
        if (i < P) part[i] = inc - v + carry;
        carry += __shfl(inc, 63, 64);
    }
}

// per-chunk local exclusive scan + chunk base -> rs becomes exclusive scan
__global__ __launch_bounds__(256) void scan_apply(
    int* __restrict__ rs, const int* __restrict__ part, int N)
{
    __shared__ int wbase[4];
    int t = threadIdx.x, lane = t & 63, wid = t >> 6;
    int idx0 = blockIdx.x * 1024 + t * 4;
    int v0 = 0, v1 = 0, v2 = 0, v3 = 0;
    if (idx0 < N) { int4 v = *(const int4*)(rs + idx0); v0 = v.x; v1 = v.y; v2 = v.z; v3 = v.w; }
    int s = v0 + v1 + v2 + v3;
    int inc = s;
#pragma unroll
    for (int off = 1; off < 64; off <<= 1) {
        int tu = __shfl_up(inc, off, 64);
        if (lane >= off) inc += tu;
    }
    if (lane == 63) wbase[wid] = inc;
    __syncthreads();
    if (t == 0) { int a = 0; for (int k = 0; k < 4; ++k) { int x = wbase[k]; wbase[k] = a; a += x; } }
    __syncthreads();
    int excl = part[blockIdx.x] + wbase[wid] + (inc - s);
    if (idx0 < N) {
        int4 o; o.x = excl; o.y = excl + v0; o.z = excl + v0 + v1; o.w = excl + v0 + v1 + v2;
        *(int4*)(rs + idx0) = o;
    }
}

// scatter; leaves rs[r] = end of row r (inclusive form)
__global__ __launch_bounds__(256) void scatter_edges(
    const int* __restrict__ rows, const int* __restrict__ cols,
    const float* __restrict__ vals, int* __restrict__ rs,
    int* __restrict__ ecol, f16* __restrict__ eval, int E)
{
    int e = blockIdx.x * 256 + threadIdx.x;
    if (e < E) {
        int pos = atomicAdd(&rs[rows[e]], 1);
        ecol[pos] = cols[e];
        eval[pos] = (f16)vals[e];
    }
}

// ========================= node kernels =====================================
// k1: pre1 = log(proj(x)) -> fp16
__global__ __launch_bounds__(256) void pre_stage(
    const float* __restrict__ x, f16* __restrict__ pre, int N)
{
    const int lane = threadIdx.x & 63;
    int node = blockIdx.x * 4 + (threadIdx.x >> 6);
    if (node >= N) return;
    float e0 = hyp_proj_lane(x[(size_t)node * D + lane]);
    pre[(size_t)node * D + lane] = (f16)log_map_lane(e0);
}

// MFMA GEMM: C[M x 64] = A[M x 64] (f16) @ W[64 x 64] (f32), C f16
// fragment layouts per cdna_hip_programming.md §3 (verified on gfx950):
//   A: lane holds A[m=lane&15][k=quad*8+j], j=0..7   (quad = lane>>4)
//   B: lane holds B[k=quad*8+j][n=lane&15]
//   D: col=lane&15, row=quad*4+reg
__global__ __launch_bounds__(256) void gemm64(
    const f16* __restrict__ A, const float* __restrict__ W,
    f16* __restrict__ C, int M)
{
    const int lane = threadIdx.x & 63;
    const int wid = blockIdx.x * 4 + (threadIdx.x >> 6);
    const int nwaves = gridDim.x * 4;
    const int m = lane & 15;
    const int quad = lane >> 4;

    f16x8 Bfr[2][4];
#pragma unroll
    for (int kt = 0; kt < 2; ++kt)
#pragma unroll
        for (int nt = 0; nt < 4; ++nt) {
            f16x8 tmp;
#pragma unroll
            for (int j = 0; j < 8; ++j)
                tmp[j] = (f16)W[(kt * 32 + quad * 8 + j) * D + nt * 16 + m];
            Bfr[kt][nt] = tmp;
        }

    const int ntile = M >> 4;               // M % 16 == 0 (N = 100000)
    for (int tile = wid; tile < ntile; tile += nwaves) {
        const f16* arow = A + (size_t)(tile * 16 + m) * D;
        f16x8 a0 = *(const f16x8*)(arow + quad * 8);
        f16x8 a1 = *(const f16x8*)(arow + 32 + quad * 8);
#pragma unroll
        for (int nt = 0; nt < 4; ++nt) {
            f32x4 z = {0.0f, 0.0f, 0.0f, 0.0f};
            z = __builtin_amdgcn_mfma_f32_16x16x32_f16(a0, Bfr[0][nt], z, 0, 0, 0);
            z = __builtin_amdgcn_mfma_f32_16x16x32_f16(a1, Bfr[1][nt], z, 0, 0, 0);
#pragma unroll
            for (int r = 0; r < 4; ++r)
                C[(size_t)(tile * 16 + quad * 4 + r) * D + nt * 16 + m] = (f16)z[r];
        }
    }
}

// ---- CSR gather: dual-edge, f16x2 loads, fp32 accum ------------------------
__device__ __forceinline__ float csr_accumulate(
    const int* __restrict__ rs, const int* __restrict__ ecol,
    const f16* __restrict__ eval, const f16* __restrict__ h,
    int row, int lane)
{
    const int start = (row == 0) ? 0 : rs[row - 1];
    const int end = rs[row];
    const int half = lane >> 5;
    const int li = lane & 31;
    const f16x2* __restrict__ h2 = (const f16x2*)h;
    float ax = 0.0f, ay = 0.0f;

    for (int j0 = start; j0 < end; j0 += 64) {
        int c = 0; float v = 0.0f;
        if (j0 + lane < end) {
            c = ecol[j0 + lane];
            v = (float)eval[j0 + lane];
        }
        int cnt = end - j0; if (cnt > 64) cnt = 64;
        for (int t = 0; t < cnt; t += 2) {
            int et = t + half;                    // lower half: edge t, upper: t+1
            int ct = __shfl(c, et, 64);
            float vt = __shfl(v, et, 64);
            if (et >= cnt) vt = 0.0f;             // odd-tail: upper half no-op (ct safe)
            f16x2 hv = h2[(size_t)ct * 32 + li];
            ax = fmaf(vt, (float)hv[0], ax);
            ay = fmaf(vt, (float)hv[1], ay);
        }
    }
    // combine halves (same dims, disjoint edges)
    ax += __shfl_xor(ax, 32, 64);
    ay += __shfl_xor(ay, 32, 64);
    // redistribute: lane d wants dim d = component (d&1) of lane d>>1
    float gx = __shfl(ax, lane >> 1, 64);
    float gy = __shfl(ay, lane >> 1, 64);
    return (lane & 1) ? gy : gx;
}

// k2: SpMM(h) + layer-1 epilogue + residual; writes h1 (f16) and pre2 (f16)
__global__ __launch_bounds__(256) void layer1_fused(
    const int* __restrict__ rs, const int* __restrict__ ecol,
    const f16* __restrict__ eval, const f16* __restrict__ h,
    const float* __restrict__ x, const float* __restrict__ b,
    f16* __restrict__ h1_out, f16* __restrict__ pre2_out, int N)
{
    const int lane = threadIdx.x & 63;
    int row = blockIdx.x * 4 + (threadIdx.x >> 6);
    if (row >= N) return;

    float bh = hyp_proj_lane(exp_map_lane(b[lane]));
    float acc = csr_accumulate(rs, ecol, eval, h, row, lane);

    float out = hyp_proj_lane(exp_map_lane(acc));
    out = hyp_proj_lane(mobius_add_lane(out, bh));
    out = hyp_proj_lane(exp_map_lane(tanhf(log_map_lane(out))));   // activation
    float e0 = hyp_proj_lane(x[(size_t)row * D + lane]);
    float h1 = hyp_proj_lane(mobius_add_lane(out, e0));
    h1_out[(size_t)row * D + lane] = (f16)h1;
    pre2_out[(size_t)row * D + lane] = (f16)log_map_lane(h1);
}

// k3: SpMM(h2lin) + layer-2 epilogue + residual; writes final f16 over h1 slot
__global__ __launch_bounds__(256) void layer2_fused(
    const int* __restrict__ rs, const int* __restrict__ ecol,
    const f16* __restrict__ eval, const f16* __restrict__ h2lin,
    const float* __restrict__ b, f16* __restrict__ h1_inout, int N)
{
    const int lane = threadIdx.x & 63;
    int row = blockIdx.x * 4 + (threadIdx.x >> 6);
    if (row >= N) return;

    float bh = hyp_proj_lane(exp_map_lane(b[lane]));
    float acc = csr_accumulate(rs, ecol, eval, h2lin, row, lane);

    float o = hyp_proj_lane(exp_map_lane(acc));
    o = hyp_proj_lane(mobius_add_lane(o, bh));
    float h1v = (float)h1_inout[(size_t)row * D + lane];
    float h2 = hyp_proj_lane(mobius_add_lane(o, h1v));
    h1_inout[(size_t)row * D + lane] = (f16)h2;   // own row, read-then-write
}

__global__ __launch_bounds__(256) void expand_half(
    const f16* __restrict__ src, float* __restrict__ dst, int n)
{
    int i = blockIdx.x * 256 + threadIdx.x;
    if (i < n) dst[i] = (float)src[i];
}

extern "C" void kernel_launch(void* const* d_in, const int* in_sizes, int n_in,
                              void* d_out, int out_size, void* d_ws, size_t ws_size,
                              hipStream_t stream) {
    const float* x    = (const float*)d_in[0];
    const float* vals = (const float*)d_in[1];
    const float* W1   = (const float*)d_in[2];
    const float* b1   = (const float*)d_in[3];
    const float* W2   = (const float*)d_in[4];
    const float* b2   = (const float*)d_in[5];
    const int* rows   = (const int*)d_in[6];
    const int* cols   = (const int*)d_in[7];
    float* out = (float*)d_out;

    const int N = in_sizes[0] / D;
    const int E = in_sizes[1];
    const size_t nd = (size_t)N * D;

    // ws layout (32.4 MB < ws_size >= 38.4 MB):
    //   ecol E*4 | eval E*2 | h1 nd*2 | rs N*4 | part 512B
    int* ecol = (int*)d_ws;
    f16* eval = (f16*)((char*)d_ws + (size_t)E * 4);
    f16* h1   = (f16*)((char*)d_ws + (size_t)E * 6);
    int* rs   = (int*)((char*)d_ws + (size_t)E * 6 + nd * 2);
    int* part = (int*)((char*)d_ws + (size_t)E * 6 + nd * 2 + (size_t)N * 4);

    // d_out doubles as two fp16 scratch slots until the final expand
    f16* slot0 = (f16*)d_out;        // pre1, then pre2
    f16* slot1 = slot0 + nd;         // h,   then h2lin

    const int eb = (E + 255) / 256;
    const int nb = (N + 3) / 4;
    const int P  = (N + 1023) / 1024;

    // CSR build (shared by both layers)
    hipMemsetAsync(rs, 0, (size_t)N * 4, stream);
    count_rows<<<eb, 256, 0, stream>>>(rows, rs, E);
    chunk_reduce<<<P, 256, 0, stream>>>(rs, part, N);
    scan_parts<<<1, 64, 0, stream>>>(part, P);
    scan_apply<<<P, 256, 0, stream>>>(rs, part, N);
    scatter_edges<<<eb, 256, 0, stream>>>(rows, cols, vals, rs, ecol, eval, E);

    // pipeline
    pre_stage<<<nb, 256, 0, stream>>>(x, slot0, N);                       // pre1
    gemm64<<<784, 256, 0, stream>>>(slot0, W1, slot1, N);                 // h = pre1@W1
    layer1_fused<<<nb, 256, 0, stream>>>(rs, ecol, eval, slot1, x, b1, h1, slot0, N); // h1, pre2
    gemm64<<<784, 256, 0, stream>>>(slot0, W2, slot1, N);                 // h2lin = pre2@W2
    layer2_fused<<<nb, 256, 0, stream>>>(rs, ecol, eval, slot1, b2, h1, N);
    expand_half<<<(int)((nd + 255) / 256), 256, 0, stream>>>(h1, out, (int)nd);
}

// Round 6
// 800.023 us; speedup vs baseline: 2.4172x; 1.0972x over previous
//
#include <hip/hip_runtime.h>
#include <math.h>

#define D 64
#define EPSF 1e-6f
#define EPS2F 1e-12f
#define PROJ_EPSF 1e-5f
#define NBANDS 8

typedef _Float16 f16;
typedef f16 f16x4 __attribute__((ext_vector_type(4)));
typedef f16 f16x8 __attribute__((ext_vector_type(8)));
typedef float f32x4 __attribute__((ext_vector_type(4)));

// ---- wave-wide sum (64 lanes) ----------------------------------------------
__device__ __forceinline__ float wave_sum(float v) {
#pragma unroll
    for (int o = 32; o > 0; o >>= 1) v += __shfl_xor(v, o, 64);
    return v;
}

__device__ __forceinline__ float hyp_proj_lane(float x) {
    float n = sqrtf(fmaxf(wave_sum(x * x), EPS2F));
    return x * fminf((1.0f - PROJ_EPSF) / n, 1.0f);
}
__device__ __forceinline__ float exp_map_lane(float v) {
    float n = sqrtf(fmaxf(wave_sum(v * v), EPS2F));
    return tanhf(n) * v / n;
}
__device__ __forceinline__ float log_map_lane(float y) {
    float n = sqrtf(fmaxf(wave_sum(y * y), EPS2F));
    return atanhf(fminf(n, 1.0f - PROJ_EPSF)) * y / n;
}
__device__ __forceinline__ float mobius_add_lane(float x, float y) {
    float x2 = wave_sum(x * x);
    float y2 = wave_sum(y * y);
    float xy = wave_sum(x * y);
    float num = (1.0f + 2.0f * xy + y2) * x + (1.0f - x2) * y;
    float den = 1.0f + 2.0f * xy + x2 * y2;
    return num / fmaxf(den, EPSF);
}

// ========================= CSR build ========================================
__global__ __launch_bounds__(256) void count_rows(
    const int* __restrict__ rows, int* __restrict__ rs, int E)
{
    int e = blockIdx.x * 256 + threadIdx.x;
    if (e < E) atomicAdd(&rs[__builtin_nontemporal_load(rows + e)], 1);
}

__global__ __launch_bounds__(256) void chunk_reduce(
    const int* __restrict__ rs, int* __restrict__ part, int N)
{
    __shared__ int ws[4];
    int t = threadIdx.x, lane = t & 63, wid = t >> 6;
    int idx0 = blockIdx.x * 1024 + t * 4;
    int s = 0;
    if (idx0 < N) { int4 v = *(const int4*)(rs + idx0); s = v.x + v.y + v.z + v.w; }
    s = (int)wave_sum((float)s);   // exact: sums < 2^24
    if (lane == 0) ws[wid] = s;
    __syncthreads();
    if (t == 0) part[blockIdx.x] = ws[0] + ws[1] + ws[2] + ws[3];
}

__global__ __launch_bounds__(64) void scan_parts(int* __restrict__ part, int P)
{
    int lane = threadIdx.x;
    int carry = 0;
    for (int b = 0; b < P; b += 64) {
        int i = b + lane;
        int v = (i < P) ? part[i] : 0;
        int inc = v;
#pragma unroll
        for (int off = 1; off < 64; off <<= 1) {
            int tu = __shfl_up(inc, off, 64);
            if (lane >= off) inc += tu;
        }
        if (i < P) part[i] = inc - v + carry;
        carry += __shfl(inc, 63, 64);
    }
}

__global__ __launch_bounds__(256) void scan_apply(
    int* __restrict__ rs, const int* __restrict__ part, int N)
{
    __shared__ int wbase[4];
    int t = threadIdx.x, lane = t & 63, wid = t >> 6;
    int idx0 = blockIdx.x * 1024 + t * 4;
    int v0 = 0, v1 = 0, v2 = 0, v3 = 0;
    if (idx0 < N) { int4 v = *(const int4*)(rs + idx0); v0 = v.x; v1 = v.y; v2 = v.z; v3 = v.w; }
    int s = v0 + v1 + v2 + v3;
    int inc = s;
#pragma unroll
    for (int off = 1; off < 64; off <<= 1) {
        int tu = __shfl_up(inc, off, 64);
        if (lane >= off) inc += tu;
    }
    if (lane == 63) wbase[wid] = inc;
    __syncthreads();
    if (t == 0) { int a = 0; for (int k = 0; k < 4; ++k) { int x = wbase[k]; wbase[k] = a; a += x; } }
    __syncthreads();
    int excl = part[blockIdx.x] + wbase[wid] + (inc - s);
    if (idx0 < N) {
        int4 o; o.x = excl; o.y = excl + v0; o.z = excl + v0 + v1; o.w = excl + v0 + v1 + v2;
        *(int4*)(rs + idx0) = o;
    }
}

// banded scatter: only edges with row in [r0,r1). CSR positions for that row
// range are contiguous -> write window stays L2-resident and line writes merge.
// Streaming reads are nontemporal so they don't evict the window.
__global__ __launch_bounds__(256) void scatter_band(
    const int* __restrict__ rows, const int* __restrict__ cols,
    const float* __restrict__ vals, int* __restrict__ rs,
    int* __restrict__ ecol, f16* __restrict__ eval, int E, int r0, int r1)
{
    int e = blockIdx.x * 256 + threadIdx.x;
    if (e >= E) return;
    int r = __builtin_nontemporal_load(rows + e);
    if (r < r0 || r >= r1) return;
    int pos = atomicAdd(&rs[r], 1);
    ecol[pos] = __builtin_nontemporal_load(cols + e);
    eval[pos] = (f16)__builtin_nontemporal_load(vals + e);
}

// ========================= node kernels =====================================
__global__ __launch_bounds__(256) void pre_stage(
    const float* __restrict__ x, f16* __restrict__ pre, int N)
{
    const int lane = threadIdx.x & 63;
    int node = blockIdx.x * 4 + (threadIdx.x >> 6);
    if (node >= N) return;
    float e0 = hyp_proj_lane(x[(size_t)node * D + lane]);
    pre[(size_t)node * D + lane] = (f16)log_map_lane(e0);
}

// MFMA GEMM: C[M x 64] = A[M x 64] (f16) @ W[64 x 64] (f32 -> f16), C f16
__global__ __launch_bounds__(256) void gemm64(
    const f16* __restrict__ A, const float* __restrict__ W,
    f16* __restrict__ C, int M)
{
    const int lane = threadIdx.x & 63;
    const int wid = blockIdx.x * 4 + (threadIdx.x >> 6);
    const int nwaves = gridDim.x * 4;
    const int m = lane & 15;
    const int quad = lane >> 4;

    f16x8 Bfr[2][4];
#pragma unroll
    for (int kt = 0; kt < 2; ++kt)
#pragma unroll
        for (int nt = 0; nt < 4; ++nt) {
            f16x8 tmp;
#pragma unroll
            for (int j = 0; j < 8; ++j)
                tmp[j] = (f16)W[(kt * 32 + quad * 8 + j) * D + nt * 16 + m];
            Bfr[kt][nt] = tmp;
        }

    const int ntile = M >> 4;
    for (int tile = wid; tile < ntile; tile += nwaves) {
        const f16* arow = A + (size_t)(tile * 16 + m) * D;
        f16x8 a0 = *(const f16x8*)(arow + quad * 8);
        f16x8 a1 = *(const f16x8*)(arow + 32 + quad * 8);
#pragma unroll
        for (int nt = 0; nt < 4; ++nt) {
            f32x4 z = {0.0f, 0.0f, 0.0f, 0.0f};
            z = __builtin_amdgcn_mfma_f32_16x16x32_f16(a0, Bfr[0][nt], z, 0, 0, 0);
            z = __builtin_amdgcn_mfma_f32_16x16x32_f16(a1, Bfr[1][nt], z, 0, 0, 0);
#pragma unroll
            for (int r = 0; r < 4; ++r)
                C[(size_t)(tile * 16 + quad * 4 + r) * D + nt * 16 + m] = (f16)z[r];
        }
    }
}

// ---- CSR gather: quad-edge, f16x4 loads, fp32 accum ------------------------
// lane = q*16+li; quarter q handles edges t+q; lane li covers dims [4li,4li+3].
__device__ __forceinline__ float csr_accumulate(
    const int* __restrict__ rs, const int* __restrict__ ecol,
    const f16* __restrict__ eval, const f16* __restrict__ h,
    int row, int lane)
{
    const int start = (row == 0) ? 0 : rs[row - 1];
    const int end = rs[row];
    const int q = lane >> 4;
    const int li = lane & 15;
    const f16x4* __restrict__ h4 = (const f16x4*)h;
    float a0 = 0.0f, a1 = 0.0f, a2 = 0.0f, a3 = 0.0f;

    for (int j0 = start; j0 < end; j0 += 64) {
        int c = 0; float v = 0.0f;
        if (j0 + lane < end) {                    // coalesced batch load
            c = ecol[j0 + lane];
            v = (float)eval[j0 + lane];
        }
        int cnt = end - j0; if (cnt > 64) cnt = 64;
#pragma unroll 2
        for (int t = 0; t < cnt; t += 4) {
            int et = t + q;
            int ct = __shfl(c, et, 64);
            float vt = __shfl(v, et, 64);
            if (et >= cnt) vt = 0.0f;             // tail: inactive-lane c==0, safe row
            f16x4 hv = h4[(size_t)ct * 16 + li];
            a0 = fmaf(vt, (float)hv[0], a0);
            a1 = fmaf(vt, (float)hv[1], a1);
            a2 = fmaf(vt, (float)hv[2], a2);
            a3 = fmaf(vt, (float)hv[3], a3);
        }
    }
    // sum the 4 quarters (disjoint edge sets, same dims)
    a0 += __shfl_xor(a0, 16, 64); a0 += __shfl_xor(a0, 32, 64);
    a1 += __shfl_xor(a1, 16, 64); a1 += __shfl_xor(a1, 32, 64);
    a2 += __shfl_xor(a2, 16, 64); a2 += __shfl_xor(a2, 32, 64);
    a3 += __shfl_xor(a3, 16, 64); a3 += __shfl_xor(a3, 32, 64);
    // redistribute: lane d wants dim d = 4*(d>>2) + (d&3)
    int src = lane >> 2;
    float g0 = __shfl(a0, src, 64);
    float g1 = __shfl(a1, src, 64);
    float g2 = __shfl(a2, src, 64);
    float g3 = __shfl(a3, src, 64);
    float lo = (lane & 1) ? g1 : g0;
    float hi = (lane & 1) ? g3 : g2;
    return (lane & 2) ? hi : lo;
}

// k2: SpMM(h) + layer-1 epilogue + residual; writes h1 (f16) and pre2 (f16)
__global__ __launch_bounds__(256) void layer1_fused(
    const int* __restrict__ rs, const int* __restrict__ ecol,
    const f16* __restrict__ eval, const f16* __restrict__ h,
    const float* __restrict__ x, const float* __restrict__ b,
    f16* __restrict__ h1_out, f16* __restrict__ pre2_out, int N)
{
    const int lane = threadIdx.x & 63;
    int row = blockIdx.x * 4 + (threadIdx.x >> 6);
    if (row >= N) return;

    float bh = hyp_proj_lane(exp_map_lane(b[lane]));
    float acc = csr_accumulate(rs, ecol, eval, h, row, lane);

    float out = hyp_proj_lane(exp_map_lane(acc));
    out = hyp_proj_lane(mobius_add_lane(out, bh));
    out = hyp_proj_lane(exp_map_lane(tanhf(log_map_lane(out))));
    float e0 = hyp_proj_lane(x[(size_t)row * D + lane]);
    float h1 = hyp_proj_lane(mobius_add_lane(out, e0));
    h1_out[(size_t)row * D + lane] = (f16)h1;
    pre2_out[(size_t)row * D + lane] = (f16)log_map_lane(h1);
}

// k3: SpMM(h2lin) + layer-2 epilogue + residual; final f16 over h1 slot
__global__ __launch_bounds__(256) void layer2_fused(
    const int* __restrict__ rs, const int* __restrict__ ecol,
    const f16* __restrict__ eval, const f16* __restrict__ h2lin,
    const float* __restrict__ b, f16* __restrict__ h1_inout, int N)
{
    const int lane = threadIdx.x & 63;
    int row = blockIdx.x * 4 + (threadIdx.x >> 6);
    if (row >= N) return;

    float bh = hyp_proj_lane(exp_map_lane(b[lane]));
    float acc = csr_accumulate(rs, ecol, eval, h2lin, row, lane);

    float o = hyp_proj_lane(exp_map_lane(acc));
    o = hyp_proj_lane(mobius_add_lane(o, bh));
    float h1v = (float)h1_inout[(size_t)row * D + lane];
    float h2 = hyp_proj_lane(mobius_add_lane(o, h1v));
    h1_inout[(size_t)row * D + lane] = (f16)h2;
}

__global__ __launch_bounds__(256) void expand_half(
    const f16* __restrict__ src, float* __restrict__ dst, int n)
{
    int i = blockIdx.x * 256 + threadIdx.x;
    if (i < n) dst[i] = (float)src[i];
}

extern "C" void kernel_launch(void* const* d_in, const int* in_sizes, int n_in,
                              void* d_out, int out_size, void* d_ws, size_t ws_size,
                              hipStream_t stream) {
    const float* x    = (const float*)d_in[0];
    const float* vals = (const float*)d_in[1];
    const float* W1   = (const float*)d_in[2];
    const float* b1   = (const float*)d_in[3];
    const float* W2   = (const float*)d_in[4];
    const float* b2   = (const float*)d_in[5];
    const int* rows   = (const int*)d_in[6];
    const int* cols   = (const int*)d_in[7];
    float* out = (float*)d_out;

    const int N = in_sizes[0] / D;
    const int E = in_sizes[1];
    const size_t nd = (size_t)N * D;

    // ws: ecol E*4 | eval E*2 | h1 nd*2 | rs N*4 | part (32.4 MB total)
    int* ecol = (int*)d_ws;
    f16* eval = (f16*)((char*)d_ws + (size_t)E * 4);
    f16* h1   = (f16*)((char*)d_ws + (size_t)E * 6);
    int* rs   = (int*)((char*)d_ws + (size_t)E * 6 + nd * 2);
    int* part = (int*)((char*)d_ws + (size_t)E * 6 + nd * 2 + (size_t)N * 4);

    // d_out doubles as two fp16 scratch slots until the final expand
    f16* slot0 = (f16*)d_out;        // pre1, then pre2
    f16* slot1 = slot0 + nd;         // h,   then h2lin

    const int eb = (E + 255) / 256;
    const int nb = (N + 3) / 4;
    const int P  = (N + 1023) / 1024;

    // CSR build (shared by both layers)
    hipMemsetAsync(rs, 0, (size_t)N * 4, stream);
    count_rows<<<eb, 256, 0, stream>>>(rows, rs, E);
    chunk_reduce<<<P, 256, 0, stream>>>(rs, part, N);
    scan_parts<<<1, 64, 0, stream>>>(part, P);
    scan_apply<<<P, 256, 0, stream>>>(rs, part, N);
    for (int bnd = 0; bnd < NBANDS; ++bnd) {
        int r0 = (int)((long long)bnd * N / NBANDS);
        int r1 = (int)((long long)(bnd + 1) * N / NBANDS);
        scatter_band<<<eb, 256, 0, stream>>>(rows, cols, vals, rs, ecol, eval, E, r0, r1);
    }

    // pipeline
    pre_stage<<<nb, 256, 0, stream>>>(x, slot0, N);
    gemm64<<<784, 256, 0, stream>>>(slot0, W1, slot1, N);
    layer1_fused<<<nb, 256, 0, stream>>>(rs, ecol, eval, slot1, x, b1, h1, slot0, N);
    gemm64<<<784, 256, 0, stream>>>(slot0, W2, slot1, N);
    layer2_fused<<<nb, 256, 0, stream>>>(rs, ecol, eval, slot1, b2, h1, N);
    expand_half<<<(int)((nd + 255) / 256), 256, 0, stream>>>(h1, out, (int)nd);
}

// Round 7
// 677.737 us; speedup vs baseline: 2.8533x; 1.1804x over previous
//
#include <hip/hip_runtime.h>
#include <math.h>

#define D 64
#define EPSF 1e-6f
#define EPS2F 1e-12f
#define PROJ_EPSF 1e-5f
#define NBANDS 8

typedef _Float16 f16;
typedef f16 f16x4 __attribute__((ext_vector_type(4)));
typedef f16 f16x8 __attribute__((ext_vector_type(8)));
typedef float f32x4 __attribute__((ext_vector_type(4)));

// ---- fast scalar math (1-inst hardware ops; rel err ~1e-6) ------------------
__device__ __forceinline__ float frcp(float x)  { return __builtin_amdgcn_rcpf(x); }
__device__ __forceinline__ float fsqrt(float x) { return __builtin_amdgcn_sqrtf(x); }
__device__ __forceinline__ float ftanh(float x) {          // |x| <= ~44 safe
    float e = __expf(2.0f * x);
    return (e - 1.0f) * frcp(e + 1.0f);
}
__device__ __forceinline__ float fatanh(float z) {         // z <= 1-1e-5
    return 0.5f * __logf((1.0f + z) * frcp(1.0f - z));
}

// ---- wave-wide sum (64 lanes) ----------------------------------------------
__device__ __forceinline__ float wave_sum(float v) {
#pragma unroll
    for (int o = 32; o > 0; o >>= 1) v += __shfl_xor(v, o, 64);
    return v;
}

// ========================= CSR build ========================================
__global__ __launch_bounds__(256) void count_rows(
    const int* __restrict__ rows, int* __restrict__ rs, int E)
{
    int e = blockIdx.x * 256 + threadIdx.x;
    if (e < E) atomicAdd(&rs[__builtin_nontemporal_load(rows + e)], 1);
}

__global__ __launch_bounds__(256) void chunk_reduce(
    const int* __restrict__ rs, int* __restrict__ part, int N)
{
    __shared__ int ws[4];
    int t = threadIdx.x, lane = t & 63, wid = t >> 6;
    int idx0 = blockIdx.x * 1024 + t * 4;
    int s = 0;
    if (idx0 < N) { int4 v = *(const int4*)(rs + idx0); s = v.x + v.y + v.z + v.w; }
    s = (int)wave_sum((float)s);
    if (lane == 0) ws[wid] = s;
    __syncthreads();
    if (t == 0) part[blockIdx.x] = ws[0] + ws[1] + ws[2] + ws[3];
}

__global__ __launch_bounds__(64) void scan_parts(int* __restrict__ part, int P)
{
    int lane = threadIdx.x;
    int carry = 0;
    for (int b = 0; b < P; b += 64) {
        int i = b + lane;
        int v = (i < P) ? part[i] : 0;
        int inc = v;
#pragma unroll
        for (int off = 1; off < 64; off <<= 1) {
            int tu = __shfl_up(inc, off, 64);
            if (lane >= off) inc += tu;
        }
        if (i < P) part[i] = inc - v + carry;
        carry += __shfl(inc, 63, 64);
    }
}

__global__ __launch_bounds__(256) void scan_apply(
    int* __restrict__ rs, const int* __restrict__ part, int N)
{
    __shared__ int wbase[4];
    int t = threadIdx.x, lane = t & 63, wid = t >> 6;
    int idx0 = blockIdx.x * 1024 + t * 4;
    int v0 = 0, v1 = 0, v2 = 0, v3 = 0;
    if (idx0 < N) { int4 v = *(const int4*)(rs + idx0); v0 = v.x; v1 = v.y; v2 = v.z; v3 = v.w; }
    int s = v0 + v1 + v2 + v3;
    int inc = s;
#pragma unroll
    for (int off = 1; off < 64; off <<= 1) {
        int tu = __shfl_up(inc, off, 64);
        if (lane >= off) inc += tu;
    }
    if (lane == 63) wbase[wid] = inc;
    __syncthreads();
    if (t == 0) { int a = 0; for (int k = 0; k < 4; ++k) { int x = wbase[k]; wbase[k] = a; a += x; } }
    __syncthreads();
    int excl = part[blockIdx.x] + wbase[wid] + (inc - s);
    if (idx0 < N) {
        int4 o; o.x = excl; o.y = excl + v0; o.z = excl + v0 + v1; o.w = excl + v0 + v1 + v2;
        *(int4*)(rs + idx0) = o;
    }
}

__global__ __launch_bounds__(256) void scatter_band(
    const int* __restrict__ rows, const int* __restrict__ cols,
    const float* __restrict__ vals, int* __restrict__ rs,
    int* __restrict__ ecol, f16* __restrict__ eval, int E, int r0, int r1)
{
    int e = blockIdx.x * 256 + threadIdx.x;
    if (e >= E) return;
    int r = __builtin_nontemporal_load(rows + e);
    if (r < r0 || r >= r1) return;
    int pos = atomicAdd(&rs[r], 1);
    ecol[pos] = __builtin_nontemporal_load(cols + e);
    eval[pos] = (f16)__builtin_nontemporal_load(vals + e);
}

// ========================= node kernels =====================================
// prep_bh: bhbuf[0:64)=bh1, [64:128)=bh2, [128]=nbh1, [129]=nbh2
__global__ __launch_bounds__(128) void prep_bh(
    const float* __restrict__ b1, const float* __restrict__ b2,
    float* __restrict__ bhbuf)
{
    int lane = threadIdx.x & 63, w = threadIdx.x >> 6;
    const float* b = w ? b2 : b1;
    float bv = b[lane];
    float nb = fsqrt(fmaxf(wave_sum(bv * bv), EPS2F));
    float t = ftanh(nb);
    float v = bv * (t * frcp(nb));
    float nv = t;
    float sc = fminf((1.0f - PROJ_EPSF) * frcp(fmaxf(nv, EPSF)), 1.0f);
    v *= sc; nv = fminf(nv, 1.0f - PROJ_EPSF);
    bhbuf[w * 64 + lane] = v;
    if (lane == 0) bhbuf[128 + w] = nv;
}

// pre_stage: pre1 = log(proj(x)); nbuf[row] = ||x|| (EPS-floored)
__global__ __launch_bounds__(256) void pre_stage(
    const float* __restrict__ x, f16* __restrict__ pre,
    float* __restrict__ nbuf, int N)
{
    const int lane = threadIdx.x & 63;
    int node = blockIdx.x * 4 + (threadIdx.x >> 6);
    if (node >= N) return;
    float xv = x[(size_t)node * D + lane];
    float nx = fsqrt(fmaxf(wave_sum(xv * xv), EPS2F));
    float sc = fminf((1.0f - PROJ_EPSF) * frcp(nx), 1.0f);
    float e0 = xv * sc;
    float ne0 = fminf(nx, 1.0f - PROJ_EPSF);
    float pv = e0 * (fatanh(ne0) * frcp(fmaxf(ne0, EPSF)));
    pre[(size_t)node * D + lane] = (f16)pv;
    if (lane == 0) nbuf[node] = nx;
}

// MFMA GEMM: C[M x 64] = A[M x 64] (f16) @ W[64 x 64] (f32 -> f16), C f16
__global__ __launch_bounds__(256) void gemm64(
    const f16* __restrict__ A, const float* __restrict__ W,
    f16* __restrict__ C, int M)
{
    const int lane = threadIdx.x & 63;
    const int wid = blockIdx.x * 4 + (threadIdx.x >> 6);
    const int nwaves = gridDim.x * 4;
    const int m = lane & 15;
    const int quad = lane >> 4;

    f16x8 Bfr[2][4];
#pragma unroll
    for (int kt = 0; kt < 2; ++kt)
#pragma unroll
        for (int nt = 0; nt < 4; ++nt) {
            f16x8 tmp;
#pragma unroll
            for (int j = 0; j < 8; ++j)
                tmp[j] = (f16)W[(kt * 32 + quad * 8 + j) * D + nt * 16 + m];
            Bfr[kt][nt] = tmp;
        }

    const int ntile = M >> 4;
    for (int tile = wid; tile < ntile; tile += nwaves) {
        const f16* arow = A + (size_t)(tile * 16 + m) * D;
        f16x8 a0 = *(const f16x8*)(arow + quad * 8);
        f16x8 a1 = *(const f16x8*)(arow + 32 + quad * 8);
#pragma unroll
        for (int nt = 0; nt < 4; ++nt) {
            f32x4 z = {0.0f, 0.0f, 0.0f, 0.0f};
            z = __builtin_amdgcn_mfma_f32_16x16x32_f16(a0, Bfr[0][nt], z, 0, 0, 0);
            z = __builtin_amdgcn_mfma_f32_16x16x32_f16(a1, Bfr[1][nt], z, 0, 0, 0);
#pragma unroll
            for (int r = 0; r < 4; ++r)
                C[(size_t)(tile * 16 + quad * 4 + r) * D + nt * 16 + m] = (f16)z[r];
        }
    }
}

// ---- CSR gather: quad-edge, f16x4 loads, fp32 accum ------------------------
__device__ __forceinline__ float csr_accumulate(
    const int* __restrict__ rs, const int* __restrict__ ecol,
    const f16* __restrict__ eval, const f16* __restrict__ h,
    int row, int lane)
{
    const int start = (row == 0) ? 0 : rs[row - 1];
    const int end = rs[row];
    const int q = lane >> 4;
    const int li = lane & 15;
    const f16x4* __restrict__ h4 = (const f16x4*)h;
    float a0 = 0.0f, a1 = 0.0f, a2 = 0.0f, a3 = 0.0f;

    for (int j0 = start; j0 < end; j0 += 64) {
        int c = 0; float v = 0.0f;
        if (j0 + lane < end) {                    // inactive lanes keep v=0, c=0
            c = ecol[j0 + lane];
            v = (float)eval[j0 + lane];
        }
        int cnt = end - j0; if (cnt > 64) cnt = 64;
#pragma unroll 2
        for (int t = 0; t < cnt; t += 4) {
            int et = t + q;                       // et>=cnt lanes hold v=0 -> no-op
            int ct = __shfl(c, et, 64);
            float vt = __shfl(v, et, 64);
            f16x4 hv = h4[(size_t)ct * 16 + li];
            a0 = fmaf(vt, (float)hv[0], a0);
            a1 = fmaf(vt, (float)hv[1], a1);
            a2 = fmaf(vt, (float)hv[2], a2);
            a3 = fmaf(vt, (float)hv[3], a3);
        }
    }
    a0 += __shfl_xor(a0, 16, 64); a0 += __shfl_xor(a0, 32, 64);
    a1 += __shfl_xor(a1, 16, 64); a1 += __shfl_xor(a1, 32, 64);
    a2 += __shfl_xor(a2, 16, 64); a2 += __shfl_xor(a2, 32, 64);
    a3 += __shfl_xor(a3, 16, 64); a3 += __shfl_xor(a3, 32, 64);
    int src = lane >> 2;
    float g0 = __shfl(a0, src, 64);
    float g1 = __shfl(a1, src, 64);
    float g2 = __shfl(a2, src, 64);
    float g3 = __shfl(a3, src, 64);
    float lo = (lane & 1) ? g1 : g0;
    float hi = (lane & 1) ? g3 : g2;
    return (lane & 2) ? hi : lo;
}

// k2: SpMM + layer-1 epilogue (scalar-tracked norms) + residual
// nbuf[row]: reads ||x||, writes ||h1||.
__global__ __launch_bounds__(256) void layer1_fused(
    const int* __restrict__ rs, const int* __restrict__ ecol,
    const f16* __restrict__ eval, const f16* __restrict__ h,
    const float* __restrict__ x, const float* __restrict__ bhbuf,
    float* __restrict__ nbuf, f16* __restrict__ h1_out,
    f16* __restrict__ pre2_out, int N)
{
    const int lane = threadIdx.x & 63;
    int row = blockIdx.x * 4 + (threadIdx.x >> 6);
    if (row >= N) return;

    float bh = bhbuf[lane];
    float nbh = bhbuf[128];

    float acc = csr_accumulate(rs, ecol, eval, h, row, lane);

    // exp_map + proj (norm tracked)
    float n_acc = fsqrt(fmaxf(wave_sum(acc * acc), EPS2F));        // reduction 1
    float t = ftanh(n_acc);
    float o = acc * (t * frcp(n_acc));
    float no = t;
    float sc = fminf((1.0f - PROJ_EPSF) * frcp(fmaxf(no, EPSF)), 1.0f);
    o *= sc; no = fminf(no, 1.0f - PROJ_EPSF);

    // mobius(o, bh) + proj: only xy needs a reduction
    float xy = wave_sum(o * bh);                                    // reduction 2
    float x2 = no * no, y2 = nbh * nbh;
    float rd = frcp(fmaxf(1.0f + 2.0f * xy + x2 * y2, EPSF));
    float al = (1.0f + 2.0f * xy + y2) * rd;
    float be = (1.0f - x2) * rd;
    float m = al * o + be * bh;
    float nm = fsqrt(fmaxf(al * al * x2 + be * be * y2 + 2.0f * al * be * xy, EPS2F));
    sc = fminf((1.0f - PROJ_EPSF) * frcp(fmaxf(nm, EPSF)), 1.0f);
    m *= sc; nm = fminf(nm, 1.0f - PROJ_EPSF);

    // activation: tanh(log_map(m)), then exp_map + proj
    float u = m * (fatanh(nm) * frcp(fmaxf(nm, EPSF)));
    float w = ftanh(u);                                             // per-lane
    float nw = fsqrt(fmaxf(wave_sum(w * w), EPS2F));                // reduction 3
    float tw = ftanh(nw);
    float ov = w * (tw * frcp(nw));
    float nov = tw;
    sc = fminf((1.0f - PROJ_EPSF) * frcp(fmaxf(nov, EPSF)), 1.0f);
    ov *= sc; nov = fminf(nov, 1.0f - PROJ_EPSF);

    // e0 from x with precomputed norm
    float xv = x[(size_t)row * D + lane];
    float nx = nbuf[row];
    float sce = fminf((1.0f - PROJ_EPSF) * frcp(nx), 1.0f);
    float e0 = xv * sce;
    float ne0 = fminf(nx, 1.0f - PROJ_EPSF);

    // mobius(ov, e0) + proj
    float xy2 = wave_sum(ov * e0);                                  // reduction 4
    x2 = nov * nov; y2 = ne0 * ne0;
    rd = frcp(fmaxf(1.0f + 2.0f * xy2 + x2 * y2, EPSF));
    al = (1.0f + 2.0f * xy2 + y2) * rd;
    be = (1.0f - x2) * rd;
    float h1v = al * ov + be * e0;
    float nh = fsqrt(fmaxf(al * al * x2 + be * be * y2 + 2.0f * al * be * xy2, EPS2F));
    sc = fminf((1.0f - PROJ_EPSF) * frcp(fmaxf(nh, EPSF)), 1.0f);
    h1v *= sc; nh = fminf(nh, 1.0f - PROJ_EPSF);

    h1_out[(size_t)row * D + lane] = (f16)h1v;
    if (lane == 0) nbuf[row] = nh;
    float pre2 = h1v * (fatanh(nh) * frcp(fmaxf(nh, EPSF)));
    pre2_out[(size_t)row * D + lane] = (f16)pre2;
}

// k3: SpMM + layer-2 epilogue + residual; final f16 over h1 slot
__global__ __launch_bounds__(256) void layer2_fused(
    const int* __restrict__ rs, const int* __restrict__ ecol,
    const f16* __restrict__ eval, const f16* __restrict__ h2lin,
    const float* __restrict__ bhbuf, const float* __restrict__ nbuf,
    f16* __restrict__ h1_inout, int N)
{
    const int lane = threadIdx.x & 63;
    int row = blockIdx.x * 4 + (threadIdx.x >> 6);
    if (row >= N) return;

    float bh = bhbuf[64 + lane];
    float nbh = bhbuf[129];

    float acc = csr_accumulate(rs, ecol, eval, h2lin, row, lane);

    float n_acc = fsqrt(fmaxf(wave_sum(acc * acc), EPS2F));        // reduction 1
    float t = ftanh(n_acc);
    float o = acc * (t * frcp(n_acc));
    float no = t;
    float sc = fminf((1.0f - PROJ_EPSF) * frcp(fmaxf(no, EPSF)), 1.0f);
    o *= sc; no = fminf(no, 1.0f - PROJ_EPSF);

    float xy = wave_sum(o * bh);                                    // reduction 2
    float x2 = no * no, y2 = nbh * nbh;
    float rd = frcp(fmaxf(1.0f + 2.0f * xy + x2 * y2, EPSF));
    float al = (1.0f + 2.0f * xy + y2) * rd;
    float be = (1.0f - x2) * rd;
    float m = al * o + be * bh;
    float nm = fsqrt(fmaxf(al * al * x2 + be * be * y2 + 2.0f * al * be * xy, EPS2F));
    sc = fminf((1.0f - PROJ_EPSF) * frcp(fmaxf(nm, EPSF)), 1.0f);
    m *= sc; nm = fminf(nm, 1.0f - PROJ_EPSF);

    // residual with h1 (norm from nbuf)
    float h1v = (float)h1_inout[(size_t)row * D + lane];
    float nh = nbuf[row];                                           // tracked fp32 norm
    float xy2 = wave_sum(m * h1v);                                  // reduction 3
    x2 = nm * nm; y2 = nh * nh;
    rd = frcp(fmaxf(1.0f + 2.0f * xy2 + x2 * y2, EPSF));
    al = (1.0f + 2.0f * xy2 + y2) * rd;
    be = (1.0f - x2) * rd;
    float h2 = al * m + be * h1v;
    float n2 = fsqrt(fmaxf(al * al * x2 + be * be * y2 + 2.0f * al * be * xy2, EPS2F));
    sc = fminf((1.0f - PROJ_EPSF) * frcp(fmaxf(n2, EPSF)), 1.0f);
    h2 *= sc;

    h1_inout[(size_t)row * D + lane] = (f16)h2;
}

__global__ __launch_bounds__(256) void expand_half(
    const f16* __restrict__ src, float* __restrict__ dst, int n)
{
    int i = blockIdx.x * 256 + threadIdx.x;
    if (i < n) dst[i] = (float)src[i];
}

extern "C" void kernel_launch(void* const* d_in, const int* in_sizes, int n_in,
                              void* d_out, int out_size, void* d_ws, size_t ws_size,
                              hipStream_t stream) {
    const float* x    = (const float*)d_in[0];
    const float* vals = (const float*)d_in[1];
    const float* W1   = (const float*)d_in[2];
    const float* b1   = (const float*)d_in[3];
    const float* W2   = (const float*)d_in[4];
    const float* b2   = (const float*)d_in[5];
    const int* rows   = (const int*)d_in[6];
    const int* cols   = (const int*)d_in[7];
    float* out = (float*)d_out;

    const int N = in_sizes[0] / D;
    const int E = in_sizes[1];
    const size_t nd = (size_t)N * D;

    // ws: ecol E*4 | eval E*2 | h1 nd*2 | rs N*4 | part 1KB | nbuf N*4 | bhbuf
    char* w = (char*)d_ws;
    int*   ecol  = (int*)w;
    f16*   eval  = (f16*)(w + (size_t)E * 4);
    f16*   h1    = (f16*)(w + (size_t)E * 6);
    int*   rs    = (int*)(w + (size_t)E * 6 + nd * 2);
    int*   part  = (int*)(w + (size_t)E * 6 + nd * 2 + (size_t)N * 4);
    float* nbuf  = (float*)(w + (size_t)E * 6 + nd * 2 + (size_t)N * 4 + 1024);
    float* bhbuf = (float*)(w + (size_t)E * 6 + nd * 2 + (size_t)N * 8 + 1024);

    // d_out doubles as two fp16 scratch slots until the final expand
    f16* slot0 = (f16*)d_out;        // pre1, then pre2
    f16* slot1 = slot0 + nd;         // h,   then h2lin

    const int eb = (E + 255) / 256;
    const int nb = (N + 3) / 4;
    const int P  = (N + 1023) / 1024;

    // CSR build (shared by both layers)
    hipMemsetAsync(rs, 0, (size_t)N * 4, stream);
    count_rows<<<eb, 256, 0, stream>>>(rows, rs, E);
    chunk_reduce<<<P, 256, 0, stream>>>(rs, part, N);
    scan_parts<<<1, 64, 0, stream>>>(part, P);
    scan_apply<<<P, 256, 0, stream>>>(rs, part, N);
    for (int bnd = 0; bnd < NBANDS; ++bnd) {
        int r0 = (int)((long long)bnd * N / NBANDS);
        int r1 = (int)((long long)(bnd + 1) * N / NBANDS);
        scatter_band<<<eb, 256, 0, stream>>>(rows, cols, vals, rs, ecol, eval, E, r0, r1);
    }

    // pipeline
    prep_bh<<<1, 128, 0, stream>>>(b1, b2, bhbuf);
    pre_stage<<<nb, 256, 0, stream>>>(x, slot0, nbuf, N);
    gemm64<<<784, 256, 0, stream>>>(slot0, W1, slot1, N);
    layer1_fused<<<nb, 256, 0, stream>>>(rs, ecol, eval, slot1, x, bhbuf, nbuf, h1, slot0, N);
    gemm64<<<784, 256, 0, stream>>>(slot0, W2, slot1, N);
    layer2_fused<<<nb, 256, 0, stream>>>(rs, ecol, eval, slot1, bhbuf, nbuf, h1, N);
    expand_half<<<(int)((nd + 255) / 256), 256, 0, stream>>>(h1, out, (int)nd);
}

// Round 8
// 518.052 us; speedup vs baseline: 3.7328x; 1.3082x over previous
//
#include <hip/hip_runtime.h>
#include <math.h>

#define D 64
#define EPSF 1e-6f
#define EPS2F 1e-12f
#define PROJ_EPSF 1e-5f
#define EPB 16384

typedef _Float16 f16;
typedef f16 f16x2 __attribute__((ext_vector_type(2)));
typedef f16 f16x4 __attribute__((ext_vector_type(4)));
typedef f16 f16x8 __attribute__((ext_vector_type(8)));
typedef float f32x4 __attribute__((ext_vector_type(4)));

__device__ __forceinline__ float frcp(float x)  { return __builtin_amdgcn_rcpf(x); }
__device__ __forceinline__ float fsqrt(float x) { return __builtin_amdgcn_sqrtf(x); }
__device__ __forceinline__ float ftanh(float x) {
    float e = __expf(2.0f * x);
    return (e - 1.0f) * frcp(e + 1.0f);
}
__device__ __forceinline__ float fatanh(float z) {
    return 0.5f * __logf((1.0f + z) * frcp(1.0f - z));
}

__device__ __forceinline__ float wave_sum(float v) {
#pragma unroll
    for (int o = 32; o > 0; o >>= 1) v += __shfl_xor(v, o, 64);
    return v;
}
__device__ __forceinline__ float half_sum(float v) {
#pragma unroll
    for (int o = 16; o > 0; o >>= 1) v += __shfl_xor(v, o, 64);
    return v;
}

// ========================= K1: phase-1 hist || prep_bh || pre ================
__global__ __launch_bounds__(256) void k1_hist_pre(
    const int* __restrict__ rows, const float* __restrict__ x,
    const float* __restrict__ b1, const float* __restrict__ b2,
    int* __restrict__ histT, f16* __restrict__ pre,
    float* __restrict__ nbuf, float* __restrict__ bhbuf,
    int E, int N, int nb1, int NBIN)
{
    const int bid = blockIdx.x, tid = threadIdx.x;
    const int lane = tid & 63;
    if (bid < nb1) {
        __shared__ int lh[512];
        for (int i = tid; i < NBIN; i += 256) lh[i] = 0;
        __syncthreads();
        const int e0 = bid * EPB;
#pragma unroll 4
        for (int k = 0; k < EPB / 256; ++k) {
            int e = e0 + k * 256 + tid;
            if (e < E) atomicAdd(&lh[__builtin_nontemporal_load(rows + e) >> 8], 1);
        }
        __syncthreads();
        for (int i = tid; i < NBIN; i += 256) histT[i * nb1 + bid] = lh[i];
    } else if (bid == nb1) {
        if (tid < 128) {
            int wsel = tid >> 6;
            const float* b = wsel ? b2 : b1;
            float bv = b[lane];
            float nb = fsqrt(fmaxf(wave_sum(bv * bv), EPS2F));
            float t = ftanh(nb);
            float v = bv * (t * frcp(nb));
            float nv = t;
            float sc = fminf((1.0f - PROJ_EPSF) * frcp(fmaxf(nv, EPSF)), 1.0f);
            v *= sc; nv = fminf(nv, 1.0f - PROJ_EPSF);
            bhbuf[wsel * 64 + lane] = v;
            if (lane == 0) bhbuf[128 + wsel] = nv;
        }
    } else {
        int node = (bid - nb1 - 1) * 4 + (tid >> 6);
        if (node >= N) return;
        float xv = x[(size_t)node * D + lane];
        float nx = fsqrt(fmaxf(wave_sum(xv * xv), EPS2F));
        float sc = fminf((1.0f - PROJ_EPSF) * frcp(nx), 1.0f);
        float e0 = xv * sc;
        float ne0 = fminf(nx, 1.0f - PROJ_EPSF);
        pre[(size_t)node * D + lane] = (f16)(e0 * (fatanh(ne0) * frcp(fmaxf(ne0, EPSF))));
        if (lane == 0) nbuf[node] = nx;
    }
}

__global__ __launch_bounds__(64) void scan_parts(int* __restrict__ part, int P)
{
    int lane = threadIdx.x;
    int carry = 0;
    for (int b = 0; b < P; b += 64) {
        int i = b + lane;
        int v = (i < P) ? part[i] : 0;
        int inc = v;
#pragma unroll
        for (int off = 1; off < 64; off <<= 1) {
            int tu = __shfl_up(inc, off, 64);
            if (lane >= off) inc += tu;
        }
        if (i < P) part[i] = inc - v + carry;
        carry += __shfl(inc, 63, 64);
    }
}

__global__ __launch_bounds__(256) void scan_apply(
    int* __restrict__ a, const int* __restrict__ part, int L)
{
    __shared__ int wbase[4];
    int t = threadIdx.x, lane = t & 63, wid = t >> 6;
    int idx0 = blockIdx.x * 1024 + t * 4;
    int v0 = 0, v1 = 0, v2 = 0, v3 = 0;
    if (idx0 < L) { int4 v = *(const int4*)(a + idx0); v0 = v.x; v1 = v.y; v2 = v.z; v3 = v.w; }
    int s = v0 + v1 + v2 + v3;
    int inc = s;
#pragma unroll
    for (int off = 1; off < 64; off <<= 1) {
        int tu = __shfl_up(inc, off, 64);
        if (lane >= off) inc += tu;
    }
    if (lane == 63) wbase[wid] = inc;
    __syncthreads();
    if (t == 0) { int acc = 0; for (int k = 0; k < 4; ++k) { int xx = wbase[k]; wbase[k] = acc; acc += xx; } }
    __syncthreads();
    int excl = part[blockIdx.x] + wbase[wid] + (inc - s);
    if (idx0 < L) {
        int4 o; o.x = excl; o.y = excl + v0; o.z = excl + v0 + v1; o.w = excl + v0 + v1 + v2;
        *(int4*)(a + idx0) = o;
    }
}

__device__ __forceinline__ void gemm64_body(
    const f16* __restrict__ A, const float* __restrict__ W,
    f16* __restrict__ C, int M, int wid, int nwaves, int lane)
{
    const int m = lane & 15;
    const int quad = lane >> 4;
    f16x8 Bfr[2][4];
#pragma unroll
    for (int kt = 0; kt < 2; ++kt)
#pragma unroll
        for (int nt = 0; nt < 4; ++nt) {
            f16x8 tmp;
#pragma unroll
            for (int j = 0; j < 8; ++j)
                tmp[j] = (f16)W[(kt * 32 + quad * 8 + j) * D + nt * 16 + m];
            Bfr[kt][nt] = tmp;
        }
    const int ntile = M >> 4;
    for (int tile = wid; tile < ntile; tile += nwaves) {
        const f16* arow = A + (size_t)(tile * 16 + m) * D;
        f16x8 a0 = *(const f16x8*)(arow + quad * 8);
        f16x8 a1 = *(const f16x8*)(arow + 32 + quad * 8);
#pragma unroll
        for (int nt = 0; nt < 4; ++nt) {
            f32x4 z = {0.0f, 0.0f, 0.0f, 0.0f};
            z = __builtin_amdgcn_mfma_f32_16x16x32_f16(a0, Bfr[0][nt], z, 0, 0, 0);
            z = __builtin_amdgcn_mfma_f32_16x16x32_f16(a1, Bfr[1][nt], z, 0, 0, 0);
#pragma unroll
            for (int r = 0; r < 4; ++r)
                C[(size_t)(tile * 16 + quad * 4 + r) * D + nt * 16 + m] = (f16)z[r];
        }
    }
}

__global__ __launch_bounds__(256) void k2_reduce_gemm(
    const int* __restrict__ histT, int* __restrict__ part, int Lp, int P,
    const f16* __restrict__ A, const float* __restrict__ W,
    f16* __restrict__ C, int M)
{
    const int tid = threadIdx.x, lane = tid & 63, wid4 = tid >> 6;
    if ((int)blockIdx.x < P) {
        __shared__ int ws[4];
        int idx0 = blockIdx.x * 1024 + tid * 4;
        int s = 0;
        if (idx0 < Lp) { int4 v = *(const int4*)(histT + idx0); s = v.x + v.y + v.z + v.w; }
        s = (int)wave_sum((float)s);
        if (lane == 0) ws[wid4] = s;
        __syncthreads();
        if (tid == 0) part[blockIdx.x] = ws[0] + ws[1] + ws[2] + ws[3];
    } else {
        int wid = (blockIdx.x - P) * 4 + wid4;
        int nwaves = (gridDim.x - P) * 4;
        gemm64_body(A, W, C, M, wid, nwaves, lane);
    }
}

__global__ __launch_bounds__(256) void gemm64(
    const f16* __restrict__ A, const float* __restrict__ W,
    f16* __restrict__ C, int M)
{
    gemm64_body(A, W, C, M, blockIdx.x * 4 + (threadIdx.x >> 6), gridDim.x * 4,
                threadIdx.x & 63);
}

__global__ __launch_bounds__(256) void p1_scatter(
    const int* __restrict__ rows, const int* __restrict__ cols,
    const float* __restrict__ vals, const int* __restrict__ histT,
    unsigned int* __restrict__ pay, unsigned char* __restrict__ rloc,
    int E, int nb1, int NBIN)
{
    __shared__ int cur[512];
    const int bid = blockIdx.x, tid = threadIdx.x;
    for (int i = tid; i < NBIN; i += 256) cur[i] = histT[i * nb1 + bid];
    __syncthreads();
    const int e0 = bid * EPB;
#pragma unroll 4
    for (int k = 0; k < EPB / 256; ++k) {
        int e = e0 + k * 256 + tid;
        if (e < E) {
            int r = __builtin_nontemporal_load(rows + e);
            int c = __builtin_nontemporal_load(cols + e);
            float v = __builtin_nontemporal_load(vals + e);
            unsigned int q = (unsigned int)fmaf(v, 32767.0f, 0.5f);
            unsigned int p = (q << 17) | (unsigned int)c;
            int pos = atomicAdd(&cur[r >> 8], 1);
            pay[pos] = p;
            rloc[pos] = (unsigned char)(r & 255);
        }
    }
}

__global__ __launch_bounds__(256) void band_build(
    const unsigned int* __restrict__ pay, const unsigned char* __restrict__ rloc,
    const int* __restrict__ histT, int* __restrict__ rs,
    unsigned int* __restrict__ epack, int E, int nb1, int NBIN, int N)
{
    __shared__ int lh[256];
    __shared__ int cur[256];
    __shared__ int wsum[4];
    const int b = blockIdx.x, tid = threadIdx.x;
    const int lane = tid & 63, wid = tid >> 6;
    const int segstart = histT[b * nb1];
    const int segend = (b + 1 < NBIN) ? histT[(b + 1) * nb1] : E;
    lh[tid] = 0;
    __syncthreads();
    for (int j = segstart + tid; j < segend; j += 256)
        atomicAdd(&lh[rloc[j]], 1);
    __syncthreads();
    int v = lh[tid];
    int inc = v;
#pragma unroll
    for (int off = 1; off < 64; off <<= 1) {
        int tu = __shfl_up(inc, off, 64);
        if (lane >= off) inc += tu;
    }
    if (lane == 63) wsum[wid] = inc;
    __syncthreads();
    int base = 0;
    for (int w2 = 0; w2 < wid; ++w2) base += wsum[w2];
    int excl = base + inc - v;
    cur[tid] = excl;
    int r = b * 256 + tid;
    if (r < N) rs[r] = segstart + excl + v;
    __syncthreads();
    for (int j = segstart + tid; j < segend; j += 256) {
        int pos = segstart + atomicAdd(&cur[rloc[j]], 1);
        epack[pos] = pay[j];
    }
}

__device__ __forceinline__ void csr_accum2(
    const int* __restrict__ rs, const unsigned int* __restrict__ epack,
    const f16* __restrict__ h, int row, int li, int base,
    float& a0, float& a1)
{
    const int start = (row == 0) ? 0 : rs[row - 1];
    const int end = rs[row];
    int nbat = (end - start + 31) >> 5;
    int nbo = __shfl_xor(nbat, 32, 64);
    if (nbo > nbat) nbat = nbo;
    const f16x2* __restrict__ h2 = (const f16x2*)h;
    a0 = 0.0f; a1 = 0.0f;
    for (int bb = 0; bb < nbat; ++bb) {
        int j0 = start + bb * 32;
        unsigned int p = 0;
        if (j0 + li < end) p = epack[j0 + li];
        int c = (int)(p & 131071u);
        float vf = (float)(p >> 17) * (1.0f / 32767.0f);
        int cnt = end - j0;
        cnt = cnt < 0 ? 0 : (cnt > 32 ? 32 : cnt);
        int co = __shfl_xor(cnt, 32, 64);
        int mc = cnt > co ? cnt : co;
        for (int t = 0; t < mc; ++t) {
            int ct = __shfl(c, base + t, 64);
            float vt = __shfl(vf, base + t, 64);
            f16x2 hv = h2[(size_t)ct * 32 + li];
            a0 = fmaf(vt, (float)hv[0], a0);
            a1 = fmaf(vt, (float)hv[1], a1);
        }
    }
}

__global__ __launch_bounds__(256) void layer1_fused(
    const int* __restrict__ rs, const unsigned int* __restrict__ epack,
    const f16* __restrict__ h, const float* __restrict__ x,
    const float* __restrict__ bhbuf, float* __restrict__ nbuf,
    f16* __restrict__ h1_out, f16* __restrict__ pre2_out, int N)
{
    const int lane = threadIdx.x & 63;
    const int half = lane >> 5, li = lane & 31, base = half << 5;
    int row = blockIdx.x * 8 + (threadIdx.x >> 6) * 2 + half;
    if (row >= N) return;

    float a0, a1;
    csr_accum2(rs, epack, h, row, li, base, a0, a1);

    float na = fsqrt(fmaxf(half_sum(a0 * a0 + a1 * a1), EPS2F));
    float t = ftanh(na);
    float s = t * frcp(na);
    float o0 = a0 * s, o1 = a1 * s;
    float no = t;
    float sc = fminf((1.0f - PROJ_EPSF) * frcp(fmaxf(no, EPSF)), 1.0f);
    o0 *= sc; o1 *= sc; no = fminf(no, 1.0f - PROJ_EPSF);

    float2 bp = ((const float2*)bhbuf)[li];
    float nbh = bhbuf[128];
    float xy = half_sum(o0 * bp.x + o1 * bp.y);
    float x2 = no * no, y2 = nbh * nbh;
    float rd = frcp(fmaxf(1.0f + 2.0f * xy + x2 * y2, EPSF));
    float al = (1.0f + 2.0f * xy + y2) * rd;
    float be = (1.0f - x2) * rd;
    float m0 = al * o0 + be * bp.x, m1 = al * o1 + be * bp.y;
    float nm = fsqrt(fmaxf(al * al * x2 + be * be * y2 + 2.0f * al * be * xy, EPS2F));
    sc = fminf((1.0f - PROJ_EPSF) * frcp(fmaxf(nm, EPSF)), 1.0f);
    m0 *= sc; m1 *= sc; nm = fminf(nm, 1.0f - PROJ_EPSF);

    float lg = fatanh(nm) * frcp(fmaxf(nm, EPSF));
    float w0 = ftanh(m0 * lg), w1 = ftanh(m1 * lg);
    float nw = fsqrt(fmaxf(half_sum(w0 * w0 + w1 * w1), EPS2F));
    float tw = ftanh(nw);
    s = tw * frcp(nw);
    float ov0 = w0 * s, ov1 = w1 * s;
    float nov = tw;
    sc = fminf((1.0f - PROJ_EPSF) * frcp(fmaxf(nov, EPSF)), 1.0f);
    ov0 *= sc; ov1 *= sc; nov = fminf(nov, 1.0f - PROJ_EPSF);

    float2 xp = ((const float2*)(x + (size_t)row * D))[li];
    float nx = nbuf[row];
    float sce = fminf((1.0f - PROJ_EPSF) * frcp(nx), 1.0f);
    float e00 = xp.x * sce, e01 = xp.y * sce;
    float ne0 = fminf(nx, 1.0f - PROJ_EPSF);
    float xy2 = half_sum(ov0 * e00 + ov1 * e01);
    x2 = nov * nov; y2 = ne0 * ne0;
    rd = frcp(fmaxf(1.0f + 2.0f * xy2 + x2 * y2, EPSF));
    al = (1.0f + 2.0f * xy2 + y2) * rd;
    be = (1.0f - x2) * rd;
    float h10 = al * ov0 + be * e00, h11 = al * ov1 + be * e01;
    float nh = fsqrt(fmaxf(al * al * x2 + be * be * y2 + 2.0f * al * be * xy2, EPS2F));
    sc = fminf((1.0f - PROJ_EPSF) * frcp(fmaxf(nh, EPSF)), 1.0f);
    h10 *= sc; h11 *= sc; nh = fminf(nh, 1.0f - PROJ_EPSF);

    f16x2 hp; hp[0] = (f16)h10; hp[1] = (f16)h11;
    ((f16x2*)h1_out)[(size_t)row * 32 + li] = hp;
    if (li == 0) nbuf[row] = nh;
    float lg2 = fatanh(nh) * frcp(fmaxf(nh, EPSF));
    f16x2 pp; pp[0] = (f16)(h10 * lg2); pp[1] = (f16)(h11 * lg2);
    ((f16x2*)pre2_out)[(size_t)row * 32 + li] = pp;
}

__global__ __launch_bounds__(256) void layer2_fused(
    const int* __restrict__ rs, const unsigned int* __restrict__ epack,
    const f16* __restrict__ h2lin, const float* __restrict__ bhbuf,
    const float* __restrict__ nbuf, f16* __restrict__ h1_inout, int N)
{
    const int lane = threadIdx.x & 63;
    const int half = lane >> 5, li = lane & 31, base = half << 5;
    int row = blockIdx.x * 8 + (threadIdx.x >> 6) * 2 + half;
    if (row >= N) return;

    float a0, a1;
    csr_accum2(rs, epack, h2lin, row, li, base, a0, a1);

    float na = fsqrt(fmaxf(half_sum(a0 * a0 + a1 * a1), EPS2F));
    float t = ftanh(na);
    float s = t * frcp(na);
    float o0 = a0 * s, o1 = a1 * s;
    float no = t;
    float sc = fminf((1.0f - PROJ_EPSF) * frcp(fmaxf(no, EPSF)), 1.0f);
    o0 *= sc; o1 *= sc; no = fminf(no, 1.0f - PROJ_EPSF);

    float2 bp = ((const float2*)(bhbuf + 64))[li];
    float nbh = bhbuf[129];
    float xy = half_sum(o0 * bp.x + o1 * bp.y);
    float x2 = no * no, y2 = nbh * nbh;
    float rd = frcp(fmaxf(1.0f + 2.0f * xy + x2 * y2, EPSF));
    float al = (1.0f + 2.0f * xy + y2) * rd;
    float be = (1.0f - x2) * rd;
    float m0 = al * o0 + be * bp.x, m1 = al * o1 + be * bp.y;
    float nm = fsqrt(fmaxf(al * al * x2 + be * be * y2 + 2.0f * al * be * xy, EPS2F));
    sc = fminf((1.0f - PROJ_EPSF) * frcp(fmaxf(nm, EPSF)), 1.0f);
    m0 *= sc; m1 *= sc; nm = fminf(nm, 1.0f - PROJ_EPSF);

    f16x2 hp = ((const f16x2*)h1_inout)[(size_t)row * 32 + li];
    float h10 = (float)hp[0], h11 = (float)hp[1];
    float nh = nbuf[row];
    float xy2 = half_sum(m0 * h10 + m1 * h11);
    x2 = nm * nm; y2 = nh * nh;
    rd = frcp(fmaxf(1.0f + 2.0f * xy2 + x2 * y2, EPSF));
    al = (1.0f + 2.0f * xy2 + y2) * rd;
    be = (1.0f - x2) * rd;
    float r0 = al * m0 + be * h10, r1 = al * m1 + be * h11;
    float n2 = fsqrt(fmaxf(al * al * x2 + be * be * y2 + 2.0f * al * be * xy2, EPS2F));
    sc = fminf((1.0f - PROJ_EPSF) * frcp(fmaxf(n2, EPSF)), 1.0f);
    r0 *= sc; r1 *= sc;

    f16x2 op; op[0] = (f16)r0; op[1] = (f16)r1;
    ((f16x2*)h1_inout)[(size_t)row * 32 + li] = op;
}

__global__ __launch_bounds__(256) void expand4(
    const f16* __restrict__ src, float* __restrict__ dst, int n4)
{
    int i = blockIdx.x * 256 + threadIdx.x;
    if (i < n4) {
        f16x4 v = ((const f16x4*)src)[i];
        float4 o; o.x = (float)v[0]; o.y = (float)v[1]; o.z = (float)v[2]; o.w = (float)v[3];
        ((float4*)dst)[i] = o;
    }
}

extern "C" void kernel_launch(void* const* d_in, const int* in_sizes, int n_in,
                              void* d_out, int out_size, void* d_ws, size_t ws_size,
                              hipStream_t stream) {
    const float* x    = (const float*)d_in[0];
    const float* vals = (const float*)d_in[1];
    const float* W1   = (const float*)d_in[2];
    const float* b1   = (const float*)d_in[3];
    const float* W2   = (const float*)d_in[4];
    const float* b2   = (const float*)d_in[5];
    const int* rows   = (const int*)d_in[6];
    const int* cols   = (const int*)d_in[7];
    float* out = (float*)d_out;

    const int N = in_sizes[0] / D;
    const int E = in_sizes[1];
    const size_t nd = (size_t)N * D;

    const int NBIN = (N + 255) >> 8;
    const int nb1  = (E + EPB - 1) / EPB;
    const int L    = NBIN * nb1;
    const int Lp   = ((L + 1023) / 1024) * 1024;
    const int P    = Lp / 1024;

    // ws: epack E*4 | pay E*4 (h1 alias) | rloc E | histT Lp*4 | part 1KB |
    //     rs N*4 | nbuf N*4 | bhbuf 1KB   (~31 MB total)
    char* w = (char*)d_ws;
    unsigned int*  epack = (unsigned int*)w;
    unsigned int*  pay   = (unsigned int*)(w + (size_t)E * 4);
    f16*           h1    = (f16*)(w + (size_t)E * 4);
    unsigned char* rloc  = (unsigned char*)(w + (size_t)E * 8);
    int*           histT = (int*)(w + (size_t)E * 9);
    size_t off = (size_t)E * 9 + (size_t)Lp * 4;
    int*   part  = (int*)(w + off);            off += 1024;
    int*   rs    = (int*)(w + off);            off += (size_t)N * 4;
    float* nbuf  = (float*)(w + off);          off += (size_t)N * 4;
    float* bhbuf = (float*)(w + off);

    f16* slot0 = (f16*)d_out;        // pre1, then pre2
    f16* slot1 = slot0 + nd;         // h,    then h2lin

    const int nbpre = (N + 3) / 4;
    const int nb2   = (N + 7) / 8;

    hipMemsetAsync(histT, 0, (size_t)Lp * 4, stream);
    k1_hist_pre<<<nb1 + 1 + nbpre, 256, 0, stream>>>(
        rows, x, b1, b2, histT, slot0, nbuf, bhbuf, E, N, nb1, NBIN);
    k2_reduce_gemm<<<P + 784, 256, 0, stream>>>(histT, part, Lp, P, slot0, W1, slot1, N);
    scan_parts<<<1, 64, 0, stream>>>(part, P);
    scan_apply<<<P, 256, 0, stream>>>(histT, part, Lp);
    p1_scatter<<<nb1, 256, 0, stream>>>(rows, cols, vals, histT, pay, rloc, E, nb1, NBIN);
    band_build<<<NBIN, 256, 0, stream>>>(pay, rloc, histT, rs, epack, E, nb1, NBIN, N);
    layer1_fused<<<nb2, 256, 0, stream>>>(rs, epack, slot1, x, bhbuf, nbuf, h1, slot0, N);
    gemm64<<<784, 256, 0, stream>>>(slot0, W2, slot1, N);
    layer2_fused<<<nb2, 256, 0, stream>>>(rs, epack, slot1, bhbuf, nbuf, h1, N);
    expand4<<<(int)((nd / 4 + 255) / 256), 256, 0, stream>>>(h1, out, (int)(nd / 4));
}

// Round 9
// 403.456 us; speedup vs baseline: 4.7931x; 1.2840x over previous
//
#include <hip/hip_runtime.h>
#include <math.h>

#define D 64
#define EPSF 1e-6f
#define EPS2F 1e-12f
#define PROJ_EPSF 1e-5f
#define EPB 16384

typedef _Float16 f16;
typedef f16 f16x4 __attribute__((ext_vector_type(4)));
typedef f16 f16x8 __attribute__((ext_vector_type(8)));
typedef float f32x4 __attribute__((ext_vector_type(4)));

__device__ __forceinline__ float frcp(float x)  { return __builtin_amdgcn_rcpf(x); }
__device__ __forceinline__ float fsqrt(float x) { return __builtin_amdgcn_sqrtf(x); }
__device__ __forceinline__ float ftanh(float x) {
    float e = __expf(2.0f * x);
    return (e - 1.0f) * frcp(e + 1.0f);
}
__device__ __forceinline__ float fatanh(float z) {
    return 0.5f * __logf((1.0f + z) * frcp(1.0f - z));
}

__device__ __forceinline__ float wave_sum(float v) {
#pragma unroll
    for (int o = 32; o > 0; o >>= 1) v += __shfl_xor(v, o, 64);
    return v;
}
// sum within each 16-lane quarter
__device__ __forceinline__ float qsum(float v) {
#pragma unroll
    for (int o = 1; o < 16; o <<= 1) v += __shfl_xor(v, o, 64);
    return v;
}

// ========================= K1: phase-1 hist || prep_bh || pre ================
__global__ __launch_bounds__(256) void k1_hist_pre(
    const int* __restrict__ rows, const float* __restrict__ x,
    const float* __restrict__ b1, const float* __restrict__ b2,
    int* __restrict__ histT, f16* __restrict__ pre,
    float* __restrict__ nbuf, float* __restrict__ bhbuf,
    int E, int N, int nb1, int NBIN)
{
    const int bid = blockIdx.x, tid = threadIdx.x;
    const int lane = tid & 63;
    if (bid < nb1) {
        __shared__ int lh[512];
        for (int i = tid; i < NBIN; i += 256) lh[i] = 0;
        __syncthreads();
        const int e0 = bid * EPB;
#pragma unroll 4
        for (int k = 0; k < EPB / 256; ++k) {
            int e = e0 + k * 256 + tid;
            if (e < E) atomicAdd(&lh[__builtin_nontemporal_load(rows + e) >> 8], 1);
        }
        __syncthreads();
        for (int i = tid; i < NBIN; i += 256) histT[i * nb1 + bid] = lh[i];
    } else if (bid == nb1) {
        if (tid < 128) {
            int wsel = tid >> 6;
            const float* b = wsel ? b2 : b1;
            float bv = b[lane];
            float nb = fsqrt(fmaxf(wave_sum(bv * bv), EPS2F));
            float t = ftanh(nb);
            float v = bv * (t * frcp(nb));
            float nv = t;
            float sc = fminf((1.0f - PROJ_EPSF) * frcp(fmaxf(nv, EPSF)), 1.0f);
            v *= sc; nv = fminf(nv, 1.0f - PROJ_EPSF);
            bhbuf[wsel * 64 + lane] = v;
            if (lane == 0) bhbuf[128 + wsel] = nv;
        }
    } else {
        int node = (bid - nb1 - 1) * 4 + (tid >> 6);
        if (node >= N) return;
        float xv = x[(size_t)node * D + lane];
        float nx = fsqrt(fmaxf(wave_sum(xv * xv), EPS2F));
        float sc = fminf((1.0f - PROJ_EPSF) * frcp(nx), 1.0f);
        float e0 = xv * sc;
        float ne0 = fminf(nx, 1.0f - PROJ_EPSF);
        pre[(size_t)node * D + lane] = (f16)(e0 * (fatanh(ne0) * frcp(fmaxf(ne0, EPSF))));
        if (lane == 0) nbuf[node] = nx;
    }
}

__global__ __launch_bounds__(64) void scan_parts(int* __restrict__ part, int P)
{
    int lane = threadIdx.x;
    int carry = 0;
    for (int b = 0; b < P; b += 64) {
        int i = b + lane;
        int v = (i < P) ? part[i] : 0;
        int inc = v;
#pragma unroll
        for (int off = 1; off < 64; off <<= 1) {
            int tu = __shfl_up(inc, off, 64);
            if (lane >= off) inc += tu;
        }
        if (i < P) part[i] = inc - v + carry;
        carry += __shfl(inc, 63, 64);
    }
}

__global__ __launch_bounds__(256) void scan_apply(
    int* __restrict__ a, const int* __restrict__ part, int L)
{
    __shared__ int wbase[4];
    int t = threadIdx.x, lane = t & 63, wid = t >> 6;
    int idx0 = blockIdx.x * 1024 + t * 4;
    int v0 = 0, v1 = 0, v2 = 0, v3 = 0;
    if (idx0 < L) { int4 v = *(const int4*)(a + idx0); v0 = v.x; v1 = v.y; v2 = v.z; v3 = v.w; }
    int s = v0 + v1 + v2 + v3;
    int inc = s;
#pragma unroll
    for (int off = 1; off < 64; off <<= 1) {
        int tu = __shfl_up(inc, off, 64);
        if (lane >= off) inc += tu;
    }
    if (lane == 63) wbase[wid] = inc;
    __syncthreads();
    if (t == 0) { int acc = 0; for (int k = 0; k < 4; ++k) { int xx = wbase[k]; wbase[k] = acc; acc += xx; } }
    __syncthreads();
    int excl = part[blockIdx.x] + wbase[wid] + (inc - s);
    if (idx0 < L) {
        int4 o; o.x = excl; o.y = excl + v0; o.z = excl + v0 + v1; o.w = excl + v0 + v1 + v2;
        *(int4*)(a + idx0) = o;
    }
}

__device__ __forceinline__ void gemm64_body(
    const f16* __restrict__ A, const float* __restrict__ W,
    f16* __restrict__ C, int M, int wid, int nwaves, int lane)
{
    const int m = lane & 15;
    const int quad = lane >> 4;
    f16x8 Bfr[2][4];
#pragma unroll
    for (int kt = 0; kt < 2; ++kt)
#pragma unroll
        for (int nt = 0; nt < 4; ++nt) {
            f16x8 tmp;
#pragma unroll
            for (int j = 0; j < 8; ++j)
                tmp[j] = (f16)W[(kt * 32 + quad * 8 + j) * D + nt * 16 + m];
            Bfr[kt][nt] = tmp;
        }
    const int ntile = M >> 4;
    for (int tile = wid; tile < ntile; tile += nwaves) {
        const f16* arow = A + (size_t)(tile * 16 + m) * D;
        f16x8 a0 = *(const f16x8*)(arow + quad * 8);
        f16x8 a1 = *(const f16x8*)(arow + 32 + quad * 8);
#pragma unroll
        for (int nt = 0; nt < 4; ++nt) {
            f32x4 z = {0.0f, 0.0f, 0.0f, 0.0f};
            z = __builtin_amdgcn_mfma_f32_16x16x32_f16(a0, Bfr[0][nt], z, 0, 0, 0);
            z = __builtin_amdgcn_mfma_f32_16x16x32_f16(a1, Bfr[1][nt], z, 0, 0, 0);
#pragma unroll
            for (int r = 0; r < 4; ++r)
                C[(size_t)(tile * 16 + quad * 4 + r) * D + nt * 16 + m] = (f16)z[r];
        }
    }
}

__global__ __launch_bounds__(256) void k2_reduce_gemm(
    const int* __restrict__ histT, int* __restrict__ part, int Lp, int P,
    const f16* __restrict__ A, const float* __restrict__ W,
    f16* __restrict__ C, int M)
{
    const int tid = threadIdx.x, lane = tid & 63, wid4 = tid >> 6;
    if ((int)blockIdx.x < P) {
        __shared__ int ws[4];
        int idx0 = blockIdx.x * 1024 + tid * 4;
        int s = 0;
        if (idx0 < Lp) { int4 v = *(const int4*)(histT + idx0); s = v.x + v.y + v.z + v.w; }
        s = (int)wave_sum((float)s);
        if (lane == 0) ws[wid4] = s;
        __syncthreads();
        if (tid == 0) part[blockIdx.x] = ws[0] + ws[1] + ws[2] + ws[3];
    } else {
        int wid = (blockIdx.x - P) * 4 + wid4;
        int nwaves = (gridDim.x - P) * 4;
        gemm64_body(A, W, C, M, wid, nwaves, lane);
    }
}

__global__ __launch_bounds__(256) void gemm64(
    const f16* __restrict__ A, const float* __restrict__ W,
    f16* __restrict__ C, int M)
{
    gemm64_body(A, W, C, M, blockIdx.x * 4 + (threadIdx.x >> 6), gridDim.x * 4,
                threadIdx.x & 63);
}

__global__ __launch_bounds__(256) void p1_scatter(
    const int* __restrict__ rows, const int* __restrict__ cols,
    const float* __restrict__ vals, const int* __restrict__ histT,
    unsigned int* __restrict__ pay, unsigned char* __restrict__ rloc,
    int E, int nb1, int NBIN)
{
    __shared__ int cur[512];
    const int bid = blockIdx.x, tid = threadIdx.x;
    for (int i = tid; i < NBIN; i += 256) cur[i] = histT[i * nb1 + bid];
    __syncthreads();
    const int e0 = bid * EPB;
#pragma unroll 4
    for (int k = 0; k < EPB / 256; ++k) {
        int e = e0 + k * 256 + tid;
        if (e < E) {
            int r = __builtin_nontemporal_load(rows + e);
            int c = __builtin_nontemporal_load(cols + e);
            float v = __builtin_nontemporal_load(vals + e);
            unsigned int q = (unsigned int)fmaf(v, 32767.0f, 0.5f);
            unsigned int p = (q << 17) | (unsigned int)c;
            int pos = atomicAdd(&cur[r >> 8], 1);
            pay[pos] = p;
            rloc[pos] = (unsigned char)(r & 255);
        }
    }
}

__global__ __launch_bounds__(256) void band_build(
    const unsigned int* __restrict__ pay, const unsigned char* __restrict__ rloc,
    const int* __restrict__ histT, int* __restrict__ rs,
    unsigned int* __restrict__ epack, int E, int nb1, int NBIN, int N)
{
    __shared__ int lh[256];
    __shared__ int cur[256];
    __shared__ int wsum[4];
    const int b = blockIdx.x, tid = threadIdx.x;
    const int lane = tid & 63, wid = tid >> 6;
    const int segstart = histT[b * nb1];
    const int segend = (b + 1 < NBIN) ? histT[(b + 1) * nb1] : E;
    lh[tid] = 0;
    __syncthreads();
    for (int j = segstart + tid; j < segend; j += 256)
        atomicAdd(&lh[rloc[j]], 1);
    __syncthreads();
    int v = lh[tid];
    int inc = v;
#pragma unroll
    for (int off = 1; off < 64; off <<= 1) {
        int tu = __shfl_up(inc, off, 64);
        if (lane >= off) inc += tu;
    }
    if (lane == 63) wsum[wid] = inc;
    __syncthreads();
    int base = 0;
    for (int w2 = 0; w2 < wid; ++w2) base += wsum[w2];
    int excl = base + inc - v;
    cur[tid] = excl;
    int r = b * 256 + tid;
    if (r < N) rs[r] = segstart + excl + v;
    __syncthreads();
    for (int j = segstart + tid; j < segend; j += 256) {
        int pos = segstart + atomicAdd(&cur[rloc[j]], 1);
        epack[pos] = pay[j];
    }
}

// ========================= quad-row CSR gather ===============================
// wave = 4 rows (one per 16-lane quarter); lane li covers dims [4li, 4li+4).
// Fixed 16-edge batches, step-2 unrolled inner loop -> up to 16 loads in flight.
__device__ __forceinline__ void csr_accum4(
    const int* __restrict__ rs, const unsigned int* __restrict__ epack,
    const f16* __restrict__ h, int row, int li, int qbase, float* a)
{
    const int start = (row == 0) ? 0 : rs[row - 1];
    const int end = rs[row];
    int nbat = (end - start + 15) >> 4;
#pragma unroll
    for (int o = 16; o < 64; o <<= 1) {
        int nbo = __shfl_xor(nbat, o, 64);
        nbat = nbo > nbat ? nbo : nbat;
    }
    const f16x4* __restrict__ h4 = (const f16x4*)h;
    float A0[4] = {0.f, 0.f, 0.f, 0.f}, A1[4] = {0.f, 0.f, 0.f, 0.f};
    for (int bb = 0; bb < nbat; ++bb) {
        int j = start + bb * 16 + li;
        unsigned int p = (j < end) ? epack[j] : 0u;
        int c = (int)(p & 131071u);
        float vf = (float)(p >> 17) * (1.0f / 32767.0f);
#pragma unroll
        for (int t = 0; t < 16; t += 2) {
            int   c0 = __shfl(c, qbase + t, 64);
            float v0 = __shfl(vf, qbase + t, 64);
            int   c1 = __shfl(c, qbase + t + 1, 64);
            float v1 = __shfl(vf, qbase + t + 1, 64);
            f16x4 h0 = h4[(size_t)c0 * 16 + li];
            f16x4 h1 = h4[(size_t)c1 * 16 + li];
#pragma unroll
            for (int k = 0; k < 4; ++k) {
                A0[k] = fmaf(v0, (float)h0[k], A0[k]);
                A1[k] = fmaf(v1, (float)h1[k], A1[k]);
            }
        }
    }
#pragma unroll
    for (int k = 0; k < 4; ++k) a[k] = A0[k] + A1[k];
}

// layer-1: SpMM + epilogue + residual; writes h1(f16x4), pre2(f16x4), nbuf=||h1||
__global__ __launch_bounds__(256) void layer1_fused(
    const int* __restrict__ rs, const unsigned int* __restrict__ epack,
    const f16* __restrict__ h, const float* __restrict__ x,
    const float* __restrict__ bhbuf, float* __restrict__ nbuf,
    f16* __restrict__ h1_out, f16* __restrict__ pre2_out, int N)
{
    const int lane = threadIdx.x & 63;
    const int q = lane >> 4, li = lane & 15, qbase = q << 4;
    int row = blockIdx.x * 16 + (threadIdx.x >> 6) * 4 + q;
    if (row >= N) row = N - 1;   // N%16==0 in practice; benign dup otherwise

    float a[4];
    csr_accum4(rs, epack, h, row, li, qbase, a);

    // exp_map + proj
    float na = fsqrt(fmaxf(qsum(a[0]*a[0] + a[1]*a[1] + a[2]*a[2] + a[3]*a[3]), EPS2F));
    float t = ftanh(na);
    float s = t * frcp(na);
    float o[4];
#pragma unroll
    for (int k = 0; k < 4; ++k) o[k] = a[k] * s;
    float no = t;
    float sc = fminf((1.0f - PROJ_EPSF) * frcp(fmaxf(no, EPSF)), 1.0f);
#pragma unroll
    for (int k = 0; k < 4; ++k) o[k] *= sc;
    no = fminf(no, 1.0f - PROJ_EPSF);

    // mobius with bh + proj
    float4 bp4 = ((const float4*)bhbuf)[li];
    float bh[4] = {bp4.x, bp4.y, bp4.z, bp4.w};
    float nbh = bhbuf[128];
    float xy = qsum(o[0]*bh[0] + o[1]*bh[1] + o[2]*bh[2] + o[3]*bh[3]);
    float x2 = no * no, y2 = nbh * nbh;
    float rd = frcp(fmaxf(1.0f + 2.0f * xy + x2 * y2, EPSF));
    float al = (1.0f + 2.0f * xy + y2) * rd;
    float be = (1.0f - x2) * rd;
    float m[4];
#pragma unroll
    for (int k = 0; k < 4; ++k) m[k] = al * o[k] + be * bh[k];
    float nm = fsqrt(fmaxf(al*al*x2 + be*be*y2 + 2.0f*al*be*xy, EPS2F));
    sc = fminf((1.0f - PROJ_EPSF) * frcp(fmaxf(nm, EPSF)), 1.0f);
#pragma unroll
    for (int k = 0; k < 4; ++k) m[k] *= sc;
    nm = fminf(nm, 1.0f - PROJ_EPSF);

    // activation tanh in tangent space, exp_map + proj
    float lg = fatanh(nm) * frcp(fmaxf(nm, EPSF));
    float w[4];
#pragma unroll
    for (int k = 0; k < 4; ++k) w[k] = ftanh(m[k] * lg);
    float nw = fsqrt(fmaxf(qsum(w[0]*w[0] + w[1]*w[1] + w[2]*w[2] + w[3]*w[3]), EPS2F));
    float tw = ftanh(nw);
    s = tw * frcp(nw);
    float ov[4];
#pragma unroll
    for (int k = 0; k < 4; ++k) ov[k] = w[k] * s;
    float nov = tw;
    sc = fminf((1.0f - PROJ_EPSF) * frcp(fmaxf(nov, EPSF)), 1.0f);
#pragma unroll
    for (int k = 0; k < 4; ++k) ov[k] *= sc;
    nov = fminf(nov, 1.0f - PROJ_EPSF);

    // residual with e0 (norm from nbuf)
    float4 xp4 = ((const float4*)(x + (size_t)row * D))[li];
    float xp[4] = {xp4.x, xp4.y, xp4.z, xp4.w};
    float nx = nbuf[row];
    float sce = fminf((1.0f - PROJ_EPSF) * frcp(nx), 1.0f);
    float e0[4];
#pragma unroll
    for (int k = 0; k < 4; ++k) e0[k] = xp[k] * sce;
    float ne0 = fminf(nx, 1.0f - PROJ_EPSF);
    float xy2 = qsum(ov[0]*e0[0] + ov[1]*e0[1] + ov[2]*e0[2] + ov[3]*e0[3]);
    x2 = nov * nov; y2 = ne0 * ne0;
    rd = frcp(fmaxf(1.0f + 2.0f * xy2 + x2 * y2, EPSF));
    al = (1.0f + 2.0f * xy2 + y2) * rd;
    be = (1.0f - x2) * rd;
    float h1v[4];
#pragma unroll
    for (int k = 0; k < 4; ++k) h1v[k] = al * ov[k] + be * e0[k];
    float nh = fsqrt(fmaxf(al*al*x2 + be*be*y2 + 2.0f*al*be*xy2, EPS2F));
    sc = fminf((1.0f - PROJ_EPSF) * frcp(fmaxf(nh, EPSF)), 1.0f);
#pragma unroll
    for (int k = 0; k < 4; ++k) h1v[k] *= sc;
    nh = fminf(nh, 1.0f - PROJ_EPSF);

    f16x4 hp, pp;
    float lg2 = fatanh(nh) * frcp(fmaxf(nh, EPSF));
#pragma unroll
    for (int k = 0; k < 4; ++k) { hp[k] = (f16)h1v[k]; pp[k] = (f16)(h1v[k] * lg2); }
    ((f16x4*)h1_out)[(size_t)row * 16 + li] = hp;
    ((f16x4*)pre2_out)[(size_t)row * 16 + li] = pp;
    if (li == 0) nbuf[row] = nh;
}

// layer-2: SpMM + epilogue + residual; final f16 over h1 slot
__global__ __launch_bounds__(256) void layer2_fused(
    const int* __restrict__ rs, const unsigned int* __restrict__ epack,
    const f16* __restrict__ h2lin, const float* __restrict__ bhbuf,
    const float* __restrict__ nbuf, f16* __restrict__ h1_inout, int N)
{
    const int lane = threadIdx.x & 63;
    const int q = lane >> 4, li = lane & 15, qbase = q << 4;
    int row = blockIdx.x * 16 + (threadIdx.x >> 6) * 4 + q;
    if (row >= N) row = N - 1;

    float a[4];
    csr_accum4(rs, epack, h2lin, row, li, qbase, a);

    float na = fsqrt(fmaxf(qsum(a[0]*a[0] + a[1]*a[1] + a[2]*a[2] + a[3]*a[3]), EPS2F));
    float t = ftanh(na);
    float s = t * frcp(na);
    float o[4];
#pragma unroll
    for (int k = 0; k < 4; ++k) o[k] = a[k] * s;
    float no = t;
    float sc = fminf((1.0f - PROJ_EPSF) * frcp(fmaxf(no, EPSF)), 1.0f);
#pragma unroll
    for (int k = 0; k < 4; ++k) o[k] *= sc;
    no = fminf(no, 1.0f - PROJ_EPSF);

    float4 bp4 = ((const float4*)(bhbuf + 64))[li];
    float bh[4] = {bp4.x, bp4.y, bp4.z, bp4.w};
    float nbh = bhbuf[129];
    float xy = qsum(o[0]*bh[0] + o[1]*bh[1] + o[2]*bh[2] + o[3]*bh[3]);
    float x2 = no * no, y2 = nbh * nbh;
    float rd = frcp(fmaxf(1.0f + 2.0f * xy + x2 * y2, EPSF));
    float al = (1.0f + 2.0f * xy + y2) * rd;
    float be = (1.0f - x2) * rd;
    float m[4];
#pragma unroll
    for (int k = 0; k < 4; ++k) m[k] = al * o[k] + be * bh[k];
    float nm = fsqrt(fmaxf(al*al*x2 + be*be*y2 + 2.0f*al*be*xy, EPS2F));
    sc = fminf((1.0f - PROJ_EPSF) * frcp(fmaxf(nm, EPSF)), 1.0f);
#pragma unroll
    for (int k = 0; k < 4; ++k) m[k] *= sc;
    nm = fminf(nm, 1.0f - PROJ_EPSF);

    f16x4 hp = ((const f16x4*)h1_inout)[(size_t)row * 16 + li];
    float h1v[4] = {(float)hp[0], (float)hp[1], (float)hp[2], (float)hp[3]};
    float nh = nbuf[row];
    float xy2 = qsum(m[0]*h1v[0] + m[1]*h1v[1] + m[2]*h1v[2] + m[3]*h1v[3]);
    x2 = nm * nm; y2 = nh * nh;
    rd = frcp(fmaxf(1.0f + 2.0f * xy2 + x2 * y2, EPSF));
    al = (1.0f + 2.0f * xy2 + y2) * rd;
    be = (1.0f - x2) * rd;
    float r[4];
#pragma unroll
    for (int k = 0; k < 4; ++k) r[k] = al * m[k] + be * h1v[k];
    float n2 = fsqrt(fmaxf(al*al*x2 + be*be*y2 + 2.0f*al*be*xy2, EPS2F));
    sc = fminf((1.0f - PROJ_EPSF) * frcp(fmaxf(n2, EPSF)), 1.0f);
    f16x4 op;
#pragma unroll
    for (int k = 0; k < 4; ++k) op[k] = (f16)(r[k] * sc);
    ((f16x4*)h1_inout)[(size_t)row * 16 + li] = op;
}

__global__ __launch_bounds__(256) void expand4(
    const f16* __restrict__ src, float* __restrict__ dst, int n4)
{
    int i = blockIdx.x * 256 + threadIdx.x;
    if (i < n4) {
        f16x4 v = ((const f16x4*)src)[i];
        float4 o; o.x = (float)v[0]; o.y = (float)v[1]; o.z = (float)v[2]; o.w = (float)v[3];
        ((float4*)dst)[i] = o;
    }
}

extern "C" void kernel_launch(void* const* d_in, const int* in_sizes, int n_in,
                              void* d_out, int out_size, void* d_ws, size_t ws_size,
                              hipStream_t stream) {
    const float* x    = (const float*)d_in[0];
    const float* vals = (const float*)d_in[1];
    const float* W1   = (const float*)d_in[2];
    const float* b1   = (const float*)d_in[3];
    const float* W2   = (const float*)d_in[4];
    const float* b2   = (const float*)d_in[5];
    const int* rows   = (const int*)d_in[6];
    const int* cols   = (const int*)d_in[7];
    float* out = (float*)d_out;

    const int N = in_sizes[0] / D;
    const int E = in_sizes[1];
    const size_t nd = (size_t)N * D;

    const int NBIN = (N + 255) >> 8;
    const int nb1  = (E + EPB - 1) / EPB;
    const int L    = NBIN * nb1;
    const int Lp   = ((L + 1023) / 1024) * 1024;
    const int P    = Lp / 1024;

    // ws: epack E*4 | pay E*4 (h1 alias) | rloc E | histT Lp*4 | part 1KB |
    //     rs N*4 | nbuf N*4 | bhbuf 1KB   (~31 MB total)
    char* w = (char*)d_ws;
    unsigned int*  epack = (unsigned int*)w;
    unsigned int*  pay   = (unsigned int*)(w + (size_t)E * 4);
    f16*           h1    = (f16*)(w + (size_t)E * 4);
    unsigned char* rloc  = (unsigned char*)(w + (size_t)E * 8);
    int*           histT = (int*)(w + (size_t)E * 9);
    size_t off = (size_t)E * 9 + (size_t)Lp * 4;
    int*   part  = (int*)(w + off);            off += 1024;
    int*   rs    = (int*)(w + off);            off += (size_t)N * 4;
    float* nbuf  = (float*)(w + off);          off += (size_t)N * 4;
    float* bhbuf = (float*)(w + off);

    f16* slot0 = (f16*)d_out;        // pre1, then pre2
    f16* slot1 = slot0 + nd;         // h,    then h2lin

    const int nbpre = (N + 3) / 4;
    const int nbq   = (N + 15) / 16;

    hipMemsetAsync(histT, 0, (size_t)Lp * 4, stream);
    k1_hist_pre<<<nb1 + 1 + nbpre, 256, 0, stream>>>(
        rows, x, b1, b2, histT, slot0, nbuf, bhbuf, E, N, nb1, NBIN);
    k2_reduce_gemm<<<P + 784, 256, 0, stream>>>(histT, part, Lp, P, slot0, W1, slot1, N);
    scan_parts<<<1, 64, 0, stream>>>(part, P);
    scan_apply<<<P, 256, 0, stream>>>(histT, part, Lp);
    p1_scatter<<<nb1, 256, 0, stream>>>(rows, cols, vals, histT, pay, rloc, E, nb1, NBIN);
    band_build<<<NBIN, 256, 0, stream>>>(pay, rloc, histT, rs, epack, E, nb1, NBIN, N);
    layer1_fused<<<nbq, 256, 0, stream>>>(rs, epack, slot1, x, bhbuf, nbuf, h1, slot0, N);
    gemm64<<<784, 256, 0, stream>>>(slot0, W2, slot1, N);
    layer2_fused<<<nbq, 256, 0, stream>>>(rs, epack, slot1, bhbuf, nbuf, h1, N);
    expand4<<<(int)((nd / 4 + 255) / 256), 256, 0, stream>>>(h1, out, (int)(nd / 4));
}